// Round 11
// baseline (1365.392 us; speedup 1.0000x reference)
//
#include <hip/hip_runtime.h>
#include <hip/hip_fp16.h>
#include <math.h>

#define N_NODES 200000
#define N_EDGES 6400000
#define F_INF   512
#define HID     16
#define NCLS    7

#define NPB      1024                              // nodes per bucket
#define NBUCKET  ((N_NODES + NPB - 1) / NPB)       // 196
#define CHUNK    16384
#define NBLKE    ((N_EDGES + CHUNK - 1) / CHUNK)   // 391

// ---- gemm1 (MFMA) geometry ----
#define GROWS 64     // rows per block (4 waves x 16)
#define KCHG  256    // K-chunk in fp32 elems (2 chunks of 256 = 512)
#define ASTR  264    // LDS row stride in halves (528B = 4 banks mod 32 -> uniform)

#define AGPAD  17    // layer-1 LDS accumulator pad (floats per node)
#define AG2PAD 9     // layer-2 LDS accumulator pad

typedef _Float16 f16x8 __attribute__((ext_vector_type(8)));
typedef float    f32x4 __attribute__((ext_vector_type(4)));

// ======================= pack (W1[0]|W1[1]|root1) into MFMA B-fragment order ========
__global__ __launch_bounds__(256) void packB_kernel(
    const float* __restrict__ W1, const float* __restrict__ root1,
    __half* __restrict__ Bf) {
    int tt = blockIdx.x * 256 + threadIdx.x;    // 3*16*64 = 3072
    if (tt >= 3 * 16 * 64) return;
    int lane = tt & 63, kk = (tt >> 6) & 15, t = tt >> 10;
    int col = lane & 15;
    int kbase = kk * 32 + (lane >> 4) * 8;
    const float* __restrict__ srcm = (t == 0) ? W1
                                   : (t == 1) ? (W1 + F_INF * HID) : root1;
    #pragma unroll
    for (int j = 0; j < 8; ++j)
        Bf[(size_t)tt * 8 + j] = __float2half(srcm[(kbase + j) * HID + col]);
}

// ======================= layer 1 GEMM via MFMA =======================
__global__ __launch_bounds__(256) void gemm1_kernel(
    const float* __restrict__ x, const __half* __restrict__ Bf,
    __half2* __restrict__ hbufH, __half* __restrict__ rbufH) {
    __shared__ __half As[GROWS * ASTR];          // 33792 B
    int tid = threadIdx.x;
    int l = tid & 63, w = tid >> 6;
    int rowBase = blockIdx.x * GROWS;

    f32x4 acc0 = {0.f, 0.f, 0.f, 0.f};
    f32x4 acc1 = {0.f, 0.f, 0.f, 0.f};
    f32x4 acc2 = {0.f, 0.f, 0.f, 0.f};

    const __half* __restrict__ Arow = &As[(w * 16 + (l & 15)) * ASTR + (l >> 4) * 8];

    for (int ch = 0; ch < F_INF / KCHG; ++ch) {  // 2 chunks
        __syncthreads();
        #pragma unroll
        for (int j = 0; j < 16; ++j) {
            int row = w * 16 + j;
            float4 v = *(const float4*)(x + (size_t)(rowBase + row) * F_INF
                                          + ch * KCHG + l * 4);
            union { __half2 h2[2]; float2 f2; } u;
            u.h2[0] = __floats2half2_rn(v.x, v.y);
            u.h2[1] = __floats2half2_rn(v.z, v.w);
            *(float2*)(&As[row * ASTR + l * 4]) = u.f2;
        }
        __syncthreads();
        #pragma unroll
        for (int kkl = 0; kkl < 8; ++kkl) {
            f16x8 a = *(const f16x8*)(Arow + kkl * 32);
            int kkg = ch * 8 + kkl;
            const __half* bp = Bf + ((size_t)kkg * 64 + l) * 8;
            f16x8 b0 = *(const f16x8*)(bp);
            f16x8 b1 = *(const f16x8*)(bp + 16 * 64 * 8);
            f16x8 b2 = *(const f16x8*)(bp + 2 * 16 * 64 * 8);
            acc0 = __builtin_amdgcn_mfma_f32_16x16x32_f16(a, b0, acc0, 0, 0, 0);
            acc1 = __builtin_amdgcn_mfma_f32_16x16x32_f16(a, b1, acc1, 0, 0, 0);
            acc2 = __builtin_amdgcn_mfma_f32_16x16x32_f16(a, b2, acc2, 0, 0, 0);
        }
    }
    int c = l & 15;
    int rbase = rowBase + w * 16 + (l >> 4) * 4;
    #pragma unroll
    for (int r = 0; r < 4; ++r) {
        int n = rbase + r;
        hbufH[(size_t)n * HID + c] = __floats2half2_rn(acc0[r], acc1[r]);
        rbufH[(size_t)n * HID + c] = __float2half(acc2[r]);
    }
}

// ======================= P1: per-block bucket histogram =======================
__global__ __launch_bounds__(256) void p1_bincount(const int* __restrict__ dst,
                                                   int* __restrict__ blockOff) {
    __shared__ int hist[NBUCKET];
    int tid = threadIdx.x;
    for (int i = tid; i < NBUCKET; i += 256) hist[i] = 0;
    __syncthreads();
    size_t base = (size_t)blockIdx.x * CHUNK;
    for (int i = 0; i < CHUNK / 256; ++i) {
        size_t e = base + (size_t)i * 256 + tid;
        if (e < N_EDGES) atomicAdd(&hist[dst[e] >> 10], 1);
    }
    __syncthreads();
    for (int i = tid; i < NBUCKET; i += 256)
        blockOff[(size_t)i * NBLKE + blockIdx.x] = hist[i];
}

// ======================= P2a: per-bucket scan over blocks =======================
__global__ __launch_bounds__(256) void p2a_kernel(int* __restrict__ blockOff,
                                                  int* __restrict__ bucketTotal) {
    __shared__ int wsum[4];
    int b = blockIdx.x, tid = threadIdx.x;
    size_t rowb = (size_t)b * NBLKE;
    int i0 = tid * 2, i1 = i0 + 1;
    int v0 = (i0 < NBLKE) ? blockOff[rowb + i0] : 0;
    int v1 = (i1 < NBLKE) ? blockOff[rowb + i1] : 0;
    int s = v0 + v1;
    int lane = tid & 63, wid = tid >> 6;
    int incl = s;
    #pragma unroll
    for (int o = 1; o < 64; o <<= 1) {
        int t = __shfl_up(incl, o, 64);
        if (lane >= o) incl += t;
    }
    if (lane == 63) wsum[wid] = incl;
    __syncthreads();
    int woff = 0;
    for (int w = 0; w < wid; ++w) woff += wsum[w];
    int excl = woff + incl - s;
    if (i0 < NBLKE) blockOff[rowb + i0] = excl;
    if (i1 < NBLKE) blockOff[rowb + i1] = excl + v0;
    if (tid == 255) bucketTotal[b] = woff + incl;
}

// ======================= P2b: scan bucket totals -> bucketStart =======================
__global__ __launch_bounds__(256) void p2b_kernel(const int* __restrict__ bucketTotal,
                                                  int* __restrict__ bucketStart) {
    __shared__ int wsum[4];
    int tid = threadIdx.x;
    int base = tid * 4;
    int v[4]; int s = 0;
    #pragma unroll
    for (int q = 0; q < 4; ++q) {
        int idx = base + q;
        v[q] = (idx < NBUCKET) ? bucketTotal[idx] : 0;
        s += v[q];
    }
    int lane = tid & 63, wid = tid >> 6;
    int incl = s;
    #pragma unroll
    for (int o = 1; o < 64; o <<= 1) {
        int t = __shfl_up(incl, o, 64);
        if (lane >= o) incl += t;
    }
    if (lane == 63) wsum[wid] = incl;
    __syncthreads();
    int woff = 0;
    for (int w = 0; w < wid; ++w) woff += wsum[w];
    int run = woff + incl - s;
    #pragma unroll
    for (int q = 0; q < 4; ++q) {
        int idx = base + q;
        if (idx < NBUCKET) bucketStart[idx] = run;
        run += v[q];
    }
}

// ======================= P3: binned scatter of payload (196 buckets) =================
// meta = (local[10b] << 18) | src[18b]
__global__ __launch_bounds__(256) void p3_binscatter(
    const int* __restrict__ dst, const int* __restrict__ src,
    const float* __restrict__ eattr,
    const int* __restrict__ blockOff, const int* __restrict__ bucketStart,
    unsigned int* __restrict__ metaArr, __half* __restrict__ wHarr) {
    __shared__ int cur[NBUCKET];
    int tid = threadIdx.x;
    for (int i = tid; i < NBUCKET; i += 256)
        cur[i] = bucketStart[i] + blockOff[(size_t)i * NBLKE + blockIdx.x];
    __syncthreads();
    size_t base = (size_t)blockIdx.x * CHUNK;
    for (int i = 0; i < CHUNK / 256; ++i) {
        size_t e = base + (size_t)i * 256 + tid;
        if (e < N_EDGES) {
            int d = dst[e];
            int b = d >> 10;
            int slot = atomicAdd(&cur[b], 1);
            unsigned int meta = ((unsigned int)(d & 1023) << 18) | (unsigned int)src[e];
            float w = fminf(fmaxf(eattr[e], 0.f), 1.f);
            metaArr[slot] = meta;
            wHarr[slot] = __float2half(w);
        }
    }
}

// ============ aggf1: bucket-level layer-1 aggregate + ELU + W2 transforms ============
// one block (1024 thr) per bucket; LDS acc [1024][17] f32 + deg[1024]
__global__ __launch_bounds__(1024) void aggf1_kernel(
    const int* __restrict__ bucketStart, const int* __restrict__ bucketTotal,
    const unsigned int* __restrict__ metaArr, const __half* __restrict__ wHarr,
    const __half2* __restrict__ hbufH, const __half* __restrict__ rbufH,
    const float* __restrict__ bias1, const float* __restrict__ W2,
    const float* __restrict__ root2,
    __half2* __restrict__ h2buf, float* __restrict__ r2buf,
    float* __restrict__ degArr) {
    __shared__ float agg[NPB * AGPAD];           // 69.6 KB
    __shared__ int degL[NPB];                    // 4 KB
    int tid = threadIdx.x, b = blockIdx.x;
    for (int i = tid; i < NPB * AGPAD; i += 1024) agg[i] = 0.f;
    for (int i = tid; i < NPB; i += 1024) degL[i] = 0;
    __syncthreads();

    int start = bucketStart[b], count = bucketTotal[b];
    int c = tid & 15, slot = tid >> 4;           // 64 edges in flight
    for (int i = slot; i < count; i += 64) {
        unsigned int m = metaArr[start + i];
        float w = __half2float(wHarr[start + i]);
        int s = (int)(m & 0x3FFFFu);
        int local = (int)(m >> 18);
        float2 h = __half22float2(hbufH[(size_t)s * HID + c]);
        atomicAdd(&agg[local * AGPAD + c], fmaf(w, h.y - h.x, h.x));
        if (c == 0) atomicAdd(&degL[local], 1);
    }
    __syncthreads();

    int n = b * NPB + tid;
    if (n >= N_NODES) return;
    float dg = (float)degL[tid];
    degArr[n] = dg;
    float inv = 1.0f / fmaxf(dg, 1.0f);
    float h[HID];
    #pragma unroll
    for (int k = 0; k < HID; ++k) {
        float v = fmaf(agg[tid * AGPAD + k], inv,
                       __half2float(rbufH[(size_t)n * HID + k])) + bias1[k];
        h[k] = v > 0.f ? v : expm1f(v);
    }
    float o0[NCLS], o1[NCLS], orr[NCLS];
    #pragma unroll
    for (int j = 0; j < NCLS; ++j) { o0[j] = 0.f; o1[j] = 0.f; orr[j] = 0.f; }
    const float* __restrict__ W2b = W2 + HID * NCLS;
    #pragma unroll
    for (int k = 0; k < HID; ++k) {
        #pragma unroll
        for (int j = 0; j < NCLS; ++j) {
            o0[j]  = fmaf(h[k], W2 [k * NCLS + j], o0[j]);
            o1[j]  = fmaf(h[k], W2b[k * NCLS + j], o1[j]);
            orr[j] = fmaf(h[k], root2[k * NCLS + j], orr[j]);
        }
    }
    __half2* hb = h2buf + (size_t)n * 8;
    float*   r2 = r2buf + (size_t)n * 8;
    #pragma unroll
    for (int j = 0; j < NCLS; ++j) {
        hb[j] = __floats2half2_rn(o0[j], o1[j]);
        r2[j] = orr[j];
    }
    hb[7] = __floats2half2_rn(0.f, 0.f);
    r2[7] = 0.f;
}

// ============ aggf2: bucket-level layer-2 aggregate + log_softmax ====================
__global__ __launch_bounds__(1024) void aggf2_kernel(
    const int* __restrict__ bucketStart, const int* __restrict__ bucketTotal,
    const unsigned int* __restrict__ metaArr, const __half* __restrict__ wHarr,
    const __half2* __restrict__ h2buf, const float* __restrict__ r2buf,
    const float* __restrict__ degArr, const float* __restrict__ bias2,
    float* __restrict__ out) {
    __shared__ float agg[NPB * AG2PAD];          // 36.9 KB
    int tid = threadIdx.x, b = blockIdx.x;
    for (int i = tid; i < NPB * AG2PAD; i += 1024) agg[i] = 0.f;
    __syncthreads();

    int start = bucketStart[b], count = bucketTotal[b];
    int j = tid & 7, slot = tid >> 3;            // 128 edges in flight
    for (int i = slot; i < count; i += 128) {
        unsigned int m = metaArr[start + i];
        float w = __half2float(wHarr[start + i]);
        int s = (int)(m & 0x3FFFFu);
        int local = (int)(m >> 18);
        float2 mm = __half22float2(h2buf[(size_t)s * 8 + j]);   // j=7 reads (0,0)
        atomicAdd(&agg[local * AG2PAD + j], fmaf(w, mm.y - mm.x, mm.x));
    }
    __syncthreads();

    int n = b * NPB + tid;
    if (n >= N_NODES) return;
    float inv = 1.0f / fmaxf(degArr[n], 1.0f);
    float v[NCLS];
    float mx = -INFINITY;
    #pragma unroll
    for (int q = 0; q < NCLS; ++q) {
        v[q] = fmaf(agg[tid * AG2PAD + q], inv, r2buf[(size_t)n * 8 + q]) + bias2[q];
        mx = fmaxf(mx, v[q]);
    }
    float sm = 0.f;
    #pragma unroll
    for (int q = 0; q < NCLS; ++q) sm += expf(v[q] - mx);
    float lse = mx + logf(sm);
    #pragma unroll
    for (int q = 0; q < NCLS; ++q) out[(size_t)n * NCLS + q] = v[q] - lse;
}

extern "C" void kernel_launch(void* const* d_in, const int* in_sizes, int n_in,
                              void* d_out, int out_size, void* d_ws, size_t ws_size,
                              hipStream_t stream) {
    const float* x     = (const float*)d_in[0];
    const float* eattr = (const float*)d_in[1];
    const int*   src   = (const int*)d_in[2];
    const int*   dst   = (const int*)d_in[3];
    const float* W1    = (const float*)d_in[4];
    const float* root1 = (const float*)d_in[5];
    const float* bias1 = (const float*)d_in[6];
    const float* W2    = (const float*)d_in[7];
    const float* root2 = (const float*)d_in[8];
    const float* bias2 = (const float*)d_in[9];
    float* out = (float*)d_out;

    // ---------- workspace layout (~72 MB) ----------
    char* wp = (char*)d_ws;
    unsigned int* metaArr = (unsigned int*)wp;  wp += (size_t)N_EDGES * 4;           // 25.6 MB
    __half*       wHarr   = (__half*)wp;        wp += (size_t)N_EDGES * 2;           // 12.8 MB
    int* blockOff    = (int*)wp;                wp += (size_t)NBUCKET * NBLKE * 4;   // 306 KB
    int* bucketTotal = (int*)wp;                wp += 1024 * 4;
    int* bucketStart = (int*)wp;                wp += 1024 * 4;
    __half* Bf       = (__half*)wp;             wp += (size_t)3 * 16 * 64 * 8 * 2;   // 48 KB
    __half2* hbufH   = (__half2*)wp;            wp += (size_t)N_NODES * HID * 4;     // 12.8 MB
    __half*  rbufH   = (__half*)wp;             wp += (size_t)N_NODES * HID * 2;     // 6.4 MB
    __half2* h2buf   = (__half2*)wp;            wp += (size_t)N_NODES * 8 * 4;       // 6.4 MB
    float*   r2buf   = (float*)wp;              wp += (size_t)N_NODES * 8 * 4;       // 6.4 MB
    float*   degArr  = (float*)wp;              wp += (size_t)N_NODES * 4;           // 0.8 MB

    hipLaunchKernelGGL(packB_kernel, dim3((3 * 16 * 64 + 255) / 256), dim3(256), 0, stream,
                       W1, root1, Bf);
    hipLaunchKernelGGL(gemm1_kernel, dim3(N_NODES / GROWS), dim3(256), 0, stream,
                       x, Bf, hbufH, rbufH);
    hipLaunchKernelGGL(p1_bincount, dim3(NBLKE), dim3(256), 0, stream, dst, blockOff);
    hipLaunchKernelGGL(p2a_kernel, dim3(NBUCKET), dim3(256), 0, stream,
                       blockOff, bucketTotal);
    hipLaunchKernelGGL(p2b_kernel, dim3(1), dim3(256), 0, stream,
                       bucketTotal, bucketStart);
    hipLaunchKernelGGL(p3_binscatter, dim3(NBLKE), dim3(256), 0, stream,
                       dst, src, eattr, blockOff, bucketStart, metaArr, wHarr);
    hipLaunchKernelGGL(aggf1_kernel, dim3(NBUCKET), dim3(1024), 0, stream,
                       bucketStart, bucketTotal, metaArr, wHarr, hbufH, rbufH,
                       bias1, W2, root2, h2buf, r2buf, degArr);
    hipLaunchKernelGGL(aggf2_kernel, dim3(NBUCKET), dim3(1024), 0, stream,
                       bucketStart, bucketTotal, metaArr, wHarr, h2buf, r2buf,
                       degArr, bias2, out);
}

// Round 12
// 1352.401 us; speedup vs baseline: 1.0096x; 1.0096x over previous
//
#include <hip/hip_runtime.h>
#include <hip/hip_fp16.h>
#include <math.h>

#define N_NODES 200000
#define N_EDGES 6400000
#define F_INF   512
#define HID     16
#define NCLS    7

#define NPB      1024                              // nodes per bucket
#define NBUCKET  ((N_NODES + NPB - 1) / NPB)       // 196
#define CHUNK    16384
#define NBLKE    ((N_EDGES + CHUNK - 1) / CHUNK)   // 391
#define SPLIT    4                                 // blocks per bucket in agg passes

// ---- gemm1 (MFMA) geometry ----
#define GROWS 64     // rows per block (4 waves x 16)
#define KCHG  256    // K-chunk in fp32 elems (2 chunks of 256 = 512)
#define ASTR  264    // LDS row stride in halves (528B = 4 banks mod 32 -> uniform)

#define AGPAD  17    // layer-1 LDS accumulator floats/node (16 ch + deg)
#define AG2PAD 9     // layer-2 LDS accumulator floats/node (8 ch + pad)

typedef _Float16 f16x8 __attribute__((ext_vector_type(8)));
typedef float    f32x4 __attribute__((ext_vector_type(4)));

// ======================= pack (W1[0]|W1[1]|root1) into MFMA B-fragment order ========
__global__ __launch_bounds__(256) void packB_kernel(
    const float* __restrict__ W1, const float* __restrict__ root1,
    __half* __restrict__ Bf) {
    int tt = blockIdx.x * 256 + threadIdx.x;    // 3*16*64 = 3072
    if (tt >= 3 * 16 * 64) return;
    int lane = tt & 63, kk = (tt >> 6) & 15, t = tt >> 10;
    int col = lane & 15;
    int kbase = kk * 32 + (lane >> 4) * 8;
    const float* __restrict__ srcm = (t == 0) ? W1
                                   : (t == 1) ? (W1 + F_INF * HID) : root1;
    #pragma unroll
    for (int j = 0; j < 8; ++j)
        Bf[(size_t)tt * 8 + j] = __float2half(srcm[(kbase + j) * HID + col]);
}

// ======================= layer 1 GEMM via MFMA =======================
__global__ __launch_bounds__(256) void gemm1_kernel(
    const float* __restrict__ x, const __half* __restrict__ Bf,
    __half2* __restrict__ hbufH, __half* __restrict__ rbufH) {
    __shared__ __half As[GROWS * ASTR];          // 33792 B
    int tid = threadIdx.x;
    int l = tid & 63, w = tid >> 6;
    int rowBase = blockIdx.x * GROWS;

    f32x4 acc0 = {0.f, 0.f, 0.f, 0.f};
    f32x4 acc1 = {0.f, 0.f, 0.f, 0.f};
    f32x4 acc2 = {0.f, 0.f, 0.f, 0.f};

    const __half* __restrict__ Arow = &As[(w * 16 + (l & 15)) * ASTR + (l >> 4) * 8];

    for (int ch = 0; ch < F_INF / KCHG; ++ch) {  // 2 chunks
        __syncthreads();
        #pragma unroll
        for (int j = 0; j < 16; ++j) {
            int row = w * 16 + j;
            float4 v = *(const float4*)(x + (size_t)(rowBase + row) * F_INF
                                          + ch * KCHG + l * 4);
            union { __half2 h2[2]; float2 f2; } u;
            u.h2[0] = __floats2half2_rn(v.x, v.y);
            u.h2[1] = __floats2half2_rn(v.z, v.w);
            *(float2*)(&As[row * ASTR + l * 4]) = u.f2;
        }
        __syncthreads();
        #pragma unroll
        for (int kkl = 0; kkl < 8; ++kkl) {
            f16x8 a = *(const f16x8*)(Arow + kkl * 32);
            int kkg = ch * 8 + kkl;
            const __half* bp = Bf + ((size_t)kkg * 64 + l) * 8;
            f16x8 b0 = *(const f16x8*)(bp);
            f16x8 b1 = *(const f16x8*)(bp + 16 * 64 * 8);
            f16x8 b2 = *(const f16x8*)(bp + 2 * 16 * 64 * 8);
            acc0 = __builtin_amdgcn_mfma_f32_16x16x32_f16(a, b0, acc0, 0, 0, 0);
            acc1 = __builtin_amdgcn_mfma_f32_16x16x32_f16(a, b1, acc1, 0, 0, 0);
            acc2 = __builtin_amdgcn_mfma_f32_16x16x32_f16(a, b2, acc2, 0, 0, 0);
        }
    }
    int c = l & 15;
    int rbase = rowBase + w * 16 + (l >> 4) * 4;
    #pragma unroll
    for (int r = 0; r < 4; ++r) {
        int n = rbase + r;
        hbufH[(size_t)n * HID + c] = __floats2half2_rn(acc0[r], acc1[r]);
        rbufH[(size_t)n * HID + c] = __float2half(acc2[r]);
    }
}

// ======================= P1: per-block bucket histogram =======================
__global__ __launch_bounds__(256) void p1_bincount(const int* __restrict__ dst,
                                                   int* __restrict__ blockOff) {
    __shared__ int hist[NBUCKET];
    int tid = threadIdx.x;
    for (int i = tid; i < NBUCKET; i += 256) hist[i] = 0;
    __syncthreads();
    size_t base = (size_t)blockIdx.x * CHUNK;
    for (int i = 0; i < CHUNK / 256; ++i) {
        size_t e = base + (size_t)i * 256 + tid;
        if (e < N_EDGES) atomicAdd(&hist[dst[e] >> 10], 1);
    }
    __syncthreads();
    for (int i = tid; i < NBUCKET; i += 256)
        blockOff[(size_t)i * NBLKE + blockIdx.x] = hist[i];
}

// ======================= P2a: per-bucket scan over blocks =======================
__global__ __launch_bounds__(256) void p2a_kernel(int* __restrict__ blockOff,
                                                  int* __restrict__ bucketTotal) {
    __shared__ int wsum[4];
    int b = blockIdx.x, tid = threadIdx.x;
    size_t rowb = (size_t)b * NBLKE;
    int i0 = tid * 2, i1 = i0 + 1;
    int v0 = (i0 < NBLKE) ? blockOff[rowb + i0] : 0;
    int v1 = (i1 < NBLKE) ? blockOff[rowb + i1] : 0;
    int s = v0 + v1;
    int lane = tid & 63, wid = tid >> 6;
    int incl = s;
    #pragma unroll
    for (int o = 1; o < 64; o <<= 1) {
        int t = __shfl_up(incl, o, 64);
        if (lane >= o) incl += t;
    }
    if (lane == 63) wsum[wid] = incl;
    __syncthreads();
    int woff = 0;
    for (int w = 0; w < wid; ++w) woff += wsum[w];
    int excl = woff + incl - s;
    if (i0 < NBLKE) blockOff[rowb + i0] = excl;
    if (i1 < NBLKE) blockOff[rowb + i1] = excl + v0;
    if (tid == 255) bucketTotal[b] = woff + incl;
}

// ======================= P2b: scan bucket totals -> bucketStart =======================
__global__ __launch_bounds__(256) void p2b_kernel(const int* __restrict__ bucketTotal,
                                                  int* __restrict__ bucketStart) {
    __shared__ int wsum[4];
    int tid = threadIdx.x;
    int base = tid * 4;
    int v[4]; int s = 0;
    #pragma unroll
    for (int q = 0; q < 4; ++q) {
        int idx = base + q;
        v[q] = (idx < NBUCKET) ? bucketTotal[idx] : 0;
        s += v[q];
    }
    int lane = tid & 63, wid = tid >> 6;
    int incl = s;
    #pragma unroll
    for (int o = 1; o < 64; o <<= 1) {
        int t = __shfl_up(incl, o, 64);
        if (lane >= o) incl += t;
    }
    if (lane == 63) wsum[wid] = incl;
    __syncthreads();
    int woff = 0;
    for (int w = 0; w < wid; ++w) woff += wsum[w];
    int run = woff + incl - s;
    #pragma unroll
    for (int q = 0; q < 4; ++q) {
        int idx = base + q;
        if (idx < NBUCKET) bucketStart[idx] = run;
        run += v[q];
    }
}

// ======================= P3: binned scatter of payload (196 buckets) =================
// meta = (local[10b] << 18) | src[18b]
__global__ __launch_bounds__(256) void p3_binscatter(
    const int* __restrict__ dst, const int* __restrict__ src,
    const float* __restrict__ eattr,
    const int* __restrict__ blockOff, const int* __restrict__ bucketStart,
    unsigned int* __restrict__ metaArr, __half* __restrict__ wHarr) {
    __shared__ int cur[NBUCKET];
    int tid = threadIdx.x;
    for (int i = tid; i < NBUCKET; i += 256)
        cur[i] = bucketStart[i] + blockOff[(size_t)i * NBLKE + blockIdx.x];
    __syncthreads();
    size_t base = (size_t)blockIdx.x * CHUNK;
    for (int i = 0; i < CHUNK / 256; ++i) {
        size_t e = base + (size_t)i * 256 + tid;
        if (e < N_EDGES) {
            int d = dst[e];
            int b = d >> 10;
            int slot = atomicAdd(&cur[b], 1);
            unsigned int meta = ((unsigned int)(d & 1023) << 18) | (unsigned int)src[e];
            float w = fminf(fmaxf(eattr[e], 0.f), 1.f);
            metaArr[slot] = meta;
            wHarr[slot] = __float2half(w);
        }
    }
}

// ============ aggf1: layer-1 bucket-slice aggregate into LDS -> partial slab =========
// grid = NBUCKET*SPLIT, block 1024; 4 lanes/edge (16B gather each)
__global__ __launch_bounds__(1024) void aggf1_kernel(
    const int* __restrict__ bucketStart, const int* __restrict__ bucketTotal,
    const unsigned int* __restrict__ metaArr, const __half* __restrict__ wHarr,
    const __half2* __restrict__ hbufH, float* __restrict__ part1) {
    __shared__ float agg[NPB * AGPAD];           // 69632 B
    int tid = threadIdx.x;
    int b = blockIdx.x >> 2, q = blockIdx.x & 3;
    for (int i = tid; i < NPB * AGPAD; i += 1024) agg[i] = 0.f;
    __syncthreads();

    int start = bucketStart[b], count = bucketTotal[b];
    int per = (count + SPLIT - 1) / SPLIT;
    int i0 = q * per, i1 = min(count, i0 + per);
    int sub = tid & 3, slot = tid >> 2;          // 256 edges in flight
    for (int i = i0 + slot; i < i1; i += 256) {
        unsigned int m = metaArr[start + i];
        float w = __half2float(wHarr[start + i]);
        int s = (int)(m & 0x3FFFFu);
        int local = (int)(m >> 18);
        union { float4 f; __half2 h[4]; } u;
        u.f = *(const float4*)(hbufH + (size_t)s * HID + sub * 4);
        #pragma unroll
        for (int p = 0; p < 4; ++p) {
            float2 h = __half22float2(u.h[p]);
            atomicAdd(&agg[local * AGPAD + sub * 4 + p], fmaf(w, h.y - h.x, h.x));
        }
        if (sub == 0) atomicAdd(&agg[local * AGPAD + 16], 1.0f);
    }
    __syncthreads();
    float* dstp = part1 + (size_t)blockIdx.x * (NPB * AGPAD);
    for (int i = tid; i < NPB * AGPAD; i += 1024) dstp[i] = agg[i];
}

// ============ fin1: merge partials + ELU + W2/root2 transforms =======================
__global__ __launch_bounds__(256) void fin1_kernel(
    const float* __restrict__ part1, const __half* __restrict__ rbufH,
    const float* __restrict__ bias1, const float* __restrict__ W2,
    const float* __restrict__ root2,
    __half2* __restrict__ h2buf, float* __restrict__ r2buf,
    float* __restrict__ degArr) {
    int n = blockIdx.x * 256 + threadIdx.x;
    if (n >= N_NODES) return;
    int b = n >> 10, local = n & 1023;
    float s[AGPAD];
    #pragma unroll
    for (int k = 0; k < AGPAD; ++k) s[k] = 0.f;
    #pragma unroll
    for (int p = 0; p < SPLIT; ++p) {
        const float* pp = part1 + (size_t)(b * SPLIT + p) * (NPB * AGPAD)
                        + (size_t)local * AGPAD;
        #pragma unroll
        for (int k = 0; k < AGPAD; ++k) s[k] += pp[k];
    }
    float dg = s[16];
    degArr[n] = dg;
    float inv = 1.0f / fmaxf(dg, 1.0f);
    float h[HID];
    #pragma unroll
    for (int k = 0; k < HID; ++k) {
        float v = fmaf(s[k], inv, __half2float(rbufH[(size_t)n * HID + k])) + bias1[k];
        h[k] = v > 0.f ? v : expm1f(v);
    }
    float o0[NCLS], o1[NCLS], orr[NCLS];
    #pragma unroll
    for (int j = 0; j < NCLS; ++j) { o0[j] = 0.f; o1[j] = 0.f; orr[j] = 0.f; }
    const float* __restrict__ W2b = W2 + HID * NCLS;
    #pragma unroll
    for (int k = 0; k < HID; ++k) {
        #pragma unroll
        for (int j = 0; j < NCLS; ++j) {
            o0[j]  = fmaf(h[k], W2 [k * NCLS + j], o0[j]);
            o1[j]  = fmaf(h[k], W2b[k * NCLS + j], o1[j]);
            orr[j] = fmaf(h[k], root2[k * NCLS + j], orr[j]);
        }
    }
    __half2* hb = h2buf + (size_t)n * 8;
    float*   r2 = r2buf + (size_t)n * 8;
    #pragma unroll
    for (int j = 0; j < NCLS; ++j) {
        hb[j] = __floats2half2_rn(o0[j], o1[j]);
        r2[j] = orr[j];
    }
    hb[7] = __floats2half2_rn(0.f, 0.f);
    r2[7] = 0.f;
}

// ============ aggf2: layer-2 bucket-slice aggregate into LDS -> partial slab =========
// 2 lanes/edge (16B gather each)
__global__ __launch_bounds__(1024) void aggf2_kernel(
    const int* __restrict__ bucketStart, const int* __restrict__ bucketTotal,
    const unsigned int* __restrict__ metaArr, const __half* __restrict__ wHarr,
    const __half2* __restrict__ h2buf, float* __restrict__ part2) {
    __shared__ float agg[NPB * AG2PAD];          // 36864 B
    int tid = threadIdx.x;
    int b = blockIdx.x >> 2, q = blockIdx.x & 3;
    for (int i = tid; i < NPB * AG2PAD; i += 1024) agg[i] = 0.f;
    __syncthreads();

    int start = bucketStart[b], count = bucketTotal[b];
    int per = (count + SPLIT - 1) / SPLIT;
    int i0 = q * per, i1 = min(count, i0 + per);
    int sub = tid & 1, slot = tid >> 1;          // 512 edges in flight
    for (int i = i0 + slot; i < i1; i += 512) {
        unsigned int m = metaArr[start + i];
        float w = __half2float(wHarr[start + i]);
        int s = (int)(m & 0x3FFFFu);
        int local = (int)(m >> 18);
        union { float4 f; __half2 h[4]; } u;
        u.f = *(const float4*)(h2buf + (size_t)s * 8 + sub * 4);
        #pragma unroll
        for (int p = 0; p < 4; ++p) {
            float2 mm = __half22float2(u.h[p]);     // channel 7 reads (0,0)
            atomicAdd(&agg[local * AG2PAD + sub * 4 + p], fmaf(w, mm.y - mm.x, mm.x));
        }
    }
    __syncthreads();
    float* dstp = part2 + (size_t)blockIdx.x * (NPB * AG2PAD);
    for (int i = tid; i < NPB * AG2PAD; i += 1024) dstp[i] = agg[i];
}

// ============ fin2: merge partials + log_softmax -> out ==============================
__global__ __launch_bounds__(256) void fin2_kernel(
    const float* __restrict__ part2, const float* __restrict__ r2buf,
    const float* __restrict__ degArr, const float* __restrict__ bias2,
    float* __restrict__ out) {
    int n = blockIdx.x * 256 + threadIdx.x;
    if (n >= N_NODES) return;
    int b = n >> 10, local = n & 1023;
    float s[8];
    #pragma unroll
    for (int k = 0; k < 8; ++k) s[k] = 0.f;
    #pragma unroll
    for (int p = 0; p < SPLIT; ++p) {
        const float* pp = part2 + (size_t)(b * SPLIT + p) * (NPB * AG2PAD)
                        + (size_t)local * AG2PAD;
        #pragma unroll
        for (int k = 0; k < 8; ++k) s[k] += pp[k];
    }
    float inv = 1.0f / fmaxf(degArr[n], 1.0f);
    float v[NCLS];
    float mx = -INFINITY;
    #pragma unroll
    for (int q = 0; q < NCLS; ++q) {
        v[q] = fmaf(s[q], inv, r2buf[(size_t)n * 8 + q]) + bias2[q];
        mx = fmaxf(mx, v[q]);
    }
    float sm = 0.f;
    #pragma unroll
    for (int q = 0; q < NCLS; ++q) sm += expf(v[q] - mx);
    float lse = mx + logf(sm);
    #pragma unroll
    for (int q = 0; q < NCLS; ++q) out[(size_t)n * NCLS + q] = v[q] - lse;
}

extern "C" void kernel_launch(void* const* d_in, const int* in_sizes, int n_in,
                              void* d_out, int out_size, void* d_ws, size_t ws_size,
                              hipStream_t stream) {
    const float* x     = (const float*)d_in[0];
    const float* eattr = (const float*)d_in[1];
    const int*   src   = (const int*)d_in[2];
    const int*   dst   = (const int*)d_in[3];
    const float* W1    = (const float*)d_in[4];
    const float* root1 = (const float*)d_in[5];
    const float* bias1 = (const float*)d_in[6];
    const float* W2    = (const float*)d_in[7];
    const float* root2 = (const float*)d_in[8];
    const float* bias2 = (const float*)d_in[9];
    float* out = (float*)d_out;

    // ---------- workspace layout (~156 MB) ----------
    char* wp = (char*)d_ws;
    unsigned int* metaArr = (unsigned int*)wp;  wp += (size_t)N_EDGES * 4;           // 25.6 MB
    __half*       wHarr   = (__half*)wp;        wp += (size_t)N_EDGES * 2;           // 12.8 MB
    int* blockOff    = (int*)wp;                wp += (size_t)NBUCKET * NBLKE * 4;   // 306 KB
    int* bucketTotal = (int*)wp;                wp += 1024 * 4;
    int* bucketStart = (int*)wp;                wp += 1024 * 4;
    __half* Bf       = (__half*)wp;             wp += (size_t)3 * 16 * 64 * 8 * 2;   // 48 KB
    __half2* hbufH   = (__half2*)wp;            wp += (size_t)N_NODES * HID * 4;     // 12.8 MB
    __half*  rbufH   = (__half*)wp;             wp += (size_t)N_NODES * HID * 2;     // 6.4 MB
    __half2* h2buf   = (__half2*)wp;            wp += (size_t)N_NODES * 8 * 4;       // 6.4 MB
    float*   r2buf   = (float*)wp;              wp += (size_t)N_NODES * 8 * 4;       // 6.4 MB
    float*   degArr  = (float*)wp;              wp += (size_t)N_NODES * 4;           // 0.8 MB
    float*   part1   = (float*)wp;              wp += (size_t)NBUCKET * SPLIT * NPB * AGPAD * 4;  // 54.6 MB
    float*   part2   = (float*)wp;              wp += (size_t)NBUCKET * SPLIT * NPB * AG2PAD * 4; // 28.9 MB

    hipLaunchKernelGGL(packB_kernel, dim3((3 * 16 * 64 + 255) / 256), dim3(256), 0, stream,
                       W1, root1, Bf);
    hipLaunchKernelGGL(gemm1_kernel, dim3(N_NODES / GROWS), dim3(256), 0, stream,
                       x, Bf, hbufH, rbufH);
    hipLaunchKernelGGL(p1_bincount, dim3(NBLKE), dim3(256), 0, stream, dst, blockOff);
    hipLaunchKernelGGL(p2a_kernel, dim3(NBUCKET), dim3(256), 0, stream,
                       blockOff, bucketTotal);
    hipLaunchKernelGGL(p2b_kernel, dim3(1), dim3(256), 0, stream,
                       bucketTotal, bucketStart);
    hipLaunchKernelGGL(p3_binscatter, dim3(NBLKE), dim3(256), 0, stream,
                       dst, src, eattr, blockOff, bucketStart, metaArr, wHarr);
    hipLaunchKernelGGL(aggf1_kernel, dim3(NBUCKET * SPLIT), dim3(1024), 0, stream,
                       bucketStart, bucketTotal, metaArr, wHarr, hbufH, part1);
    hipLaunchKernelGGL(fin1_kernel, dim3((N_NODES + 255) / 256), dim3(256), 0, stream,
                       part1, rbufH, bias1, W2, root2, h2buf, r2buf, degArr);
    hipLaunchKernelGGL(aggf2_kernel, dim3(NBUCKET * SPLIT), dim3(1024), 0, stream,
                       bucketStart, bucketTotal, metaArr, wHarr, h2buf, part2);
    hipLaunchKernelGGL(fin2_kernel, dim3((N_NODES + 255) / 256), dim3(256), 0, stream,
                       part2, r2buf, degArr, bias2, out);
}

// Round 13
// 724.942 us; speedup vs baseline: 1.8835x; 1.8655x over previous
//
#include <hip/hip_runtime.h>
#include <hip/hip_fp16.h>
#include <math.h>

#define N_NODES 200000
#define N_EDGES 6400000
#define F_INF   512
#define HID     16
#define NCLS    7

#define NPB      1024                              // nodes per bucket
#define NBUCKET  ((N_NODES + NPB - 1) / NPB)       // 196
#define CHUNK    16384
#define NBLKE    ((N_EDGES + CHUNK - 1) / CHUNK)   // 391

// ---- gemm1 (MFMA) geometry ----
#define GROWS 64     // rows per block (4 waves x 16)
#define KCHG  256    // K-chunk in fp32 elems (2 chunks of 256 = 512)
#define ASTR  264    // LDS row stride in halves (528B = 4 banks mod 32 -> uniform)

typedef _Float16 f16x8 __attribute__((ext_vector_type(8)));
typedef float    f32x4 __attribute__((ext_vector_type(4)));

// ======================= pack (W1[0]|W1[1]|root1) into MFMA B-fragment order ========
__global__ __launch_bounds__(256) void packB_kernel(
    const float* __restrict__ W1, const float* __restrict__ root1,
    __half* __restrict__ Bf) {
    int tt = blockIdx.x * 256 + threadIdx.x;    // 3*16*64 = 3072
    if (tt >= 3 * 16 * 64) return;
    int lane = tt & 63, kk = (tt >> 6) & 15, t = tt >> 10;
    int col = lane & 15;
    int kbase = kk * 32 + (lane >> 4) * 8;
    const float* __restrict__ srcm = (t == 0) ? W1
                                   : (t == 1) ? (W1 + F_INF * HID) : root1;
    #pragma unroll
    for (int j = 0; j < 8; ++j)
        Bf[(size_t)tt * 8 + j] = __float2half(srcm[(kbase + j) * HID + col]);
}

// ======================= layer 1 GEMM via MFMA =======================
__global__ __launch_bounds__(256) void gemm1_kernel(
    const float* __restrict__ x, const __half* __restrict__ Bf,
    __half2* __restrict__ hbufH, __half* __restrict__ rbufH) {
    __shared__ __half As[GROWS * ASTR];          // 33792 B
    int tid = threadIdx.x;
    int l = tid & 63, w = tid >> 6;
    int rowBase = blockIdx.x * GROWS;

    f32x4 acc0 = {0.f, 0.f, 0.f, 0.f};
    f32x4 acc1 = {0.f, 0.f, 0.f, 0.f};
    f32x4 acc2 = {0.f, 0.f, 0.f, 0.f};

    const __half* __restrict__ Arow = &As[(w * 16 + (l & 15)) * ASTR + (l >> 4) * 8];

    for (int ch = 0; ch < F_INF / KCHG; ++ch) {  // 2 chunks
        __syncthreads();
        #pragma unroll
        for (int j = 0; j < 16; ++j) {
            int row = w * 16 + j;
            float4 v = *(const float4*)(x + (size_t)(rowBase + row) * F_INF
                                          + ch * KCHG + l * 4);
            union { __half2 h2[2]; float2 f2; } u;
            u.h2[0] = __floats2half2_rn(v.x, v.y);
            u.h2[1] = __floats2half2_rn(v.z, v.w);
            *(float2*)(&As[row * ASTR + l * 4]) = u.f2;
        }
        __syncthreads();
        #pragma unroll
        for (int kkl = 0; kkl < 8; ++kkl) {
            f16x8 a = *(const f16x8*)(Arow + kkl * 32);
            int kkg = ch * 8 + kkl;
            const __half* bp = Bf + ((size_t)kkg * 64 + l) * 8;
            f16x8 b0 = *(const f16x8*)(bp);
            f16x8 b1 = *(const f16x8*)(bp + 16 * 64 * 8);
            f16x8 b2 = *(const f16x8*)(bp + 2 * 16 * 64 * 8);
            acc0 = __builtin_amdgcn_mfma_f32_16x16x32_f16(a, b0, acc0, 0, 0, 0);
            acc1 = __builtin_amdgcn_mfma_f32_16x16x32_f16(a, b1, acc1, 0, 0, 0);
            acc2 = __builtin_amdgcn_mfma_f32_16x16x32_f16(a, b2, acc2, 0, 0, 0);
        }
    }
    int c = l & 15;
    int rbase = rowBase + w * 16 + (l >> 4) * 4;
    #pragma unroll
    for (int r = 0; r < 4; ++r) {
        int n = rbase + r;
        hbufH[(size_t)n * HID + c] = __floats2half2_rn(acc0[r], acc1[r]);
        rbufH[(size_t)n * HID + c] = __float2half(acc2[r]);
    }
}

// ======================= P1: per-block bucket histogram (4 sub-hists) ================
__global__ __launch_bounds__(256) void p1_bincount(const int* __restrict__ dst,
                                                   int* __restrict__ blockOff) {
    __shared__ int hist[4][NBUCKET];
    int tid = threadIdx.x, w = tid >> 6;
    for (int i = tid; i < 4 * NBUCKET; i += 256) hist[i / NBUCKET][i % NBUCKET] = 0;
    __syncthreads();
    size_t base = (size_t)blockIdx.x * CHUNK;
    for (int i = 0; i < CHUNK / 256; ++i) {
        size_t e = base + (size_t)i * 256 + tid;
        if (e < N_EDGES) atomicAdd(&hist[w][dst[e] >> 10], 1);
    }
    __syncthreads();
    for (int i = tid; i < NBUCKET; i += 256)
        blockOff[(size_t)i * NBLKE + blockIdx.x] =
            hist[0][i] + hist[1][i] + hist[2][i] + hist[3][i];
}

// ======================= P2a: per-bucket scan over blocks =======================
__global__ __launch_bounds__(256) void p2a_kernel(int* __restrict__ blockOff,
                                                  int* __restrict__ bucketTotal) {
    __shared__ int wsum[4];
    int b = blockIdx.x, tid = threadIdx.x;
    size_t rowb = (size_t)b * NBLKE;
    int i0 = tid * 2, i1 = i0 + 1;
    int v0 = (i0 < NBLKE) ? blockOff[rowb + i0] : 0;
    int v1 = (i1 < NBLKE) ? blockOff[rowb + i1] : 0;
    int s = v0 + v1;
    int lane = tid & 63, wid = tid >> 6;
    int incl = s;
    #pragma unroll
    for (int o = 1; o < 64; o <<= 1) {
        int t = __shfl_up(incl, o, 64);
        if (lane >= o) incl += t;
    }
    if (lane == 63) wsum[wid] = incl;
    __syncthreads();
    int woff = 0;
    for (int w = 0; w < wid; ++w) woff += wsum[w];
    int excl = woff + incl - s;
    if (i0 < NBLKE) blockOff[rowb + i0] = excl;
    if (i1 < NBLKE) blockOff[rowb + i1] = excl + v0;
    if (tid == 255) bucketTotal[b] = woff + incl;
}

// ======================= P2b: scan bucket totals -> bucketStart =======================
__global__ __launch_bounds__(256) void p2b_kernel(const int* __restrict__ bucketTotal,
                                                  int* __restrict__ bucketStart,
                                                  int* __restrict__ rowptr) {
    __shared__ int wsum[4];
    int tid = threadIdx.x;
    int base = tid * 4;
    int v[4]; int s = 0;
    #pragma unroll
    for (int q = 0; q < 4; ++q) {
        int idx = base + q;
        v[q] = (idx < NBUCKET) ? bucketTotal[idx] : 0;
        s += v[q];
    }
    int lane = tid & 63, wid = tid >> 6;
    int incl = s;
    #pragma unroll
    for (int o = 1; o < 64; o <<= 1) {
        int t = __shfl_up(incl, o, 64);
        if (lane >= o) incl += t;
    }
    if (lane == 63) wsum[wid] = incl;
    __syncthreads();
    int woff = 0;
    for (int w = 0; w < wid; ++w) woff += wsum[w];
    int run = woff + incl - s;
    #pragma unroll
    for (int q = 0; q < 4; ++q) {
        int idx = base + q;
        if (idx < NBUCKET) bucketStart[idx] = run;
        run += v[q];
    }
    if (tid == 0) rowptr[N_NODES] = N_EDGES;
}

// ======================= P3: binned scatter of payload (196 buckets) =================
// meta = (local[10b] << 18) | src[18b]
__global__ __launch_bounds__(256) void p3_binscatter(
    const int* __restrict__ dst, const int* __restrict__ src,
    const float* __restrict__ eattr,
    const int* __restrict__ blockOff, const int* __restrict__ bucketStart,
    unsigned int* __restrict__ metaArr, __half* __restrict__ wHarr) {
    __shared__ int cur[NBUCKET];
    int tid = threadIdx.x;
    for (int i = tid; i < NBUCKET; i += 256)
        cur[i] = bucketStart[i] + blockOff[(size_t)i * NBLKE + blockIdx.x];
    __syncthreads();
    size_t base = (size_t)blockIdx.x * CHUNK;
    for (int i = 0; i < CHUNK / 256; ++i) {
        size_t e = base + (size_t)i * 256 + tid;
        if (e < N_EDGES) {
            int d = dst[e];
            int b = d >> 10;
            int slot = atomicAdd(&cur[b], 1);
            unsigned int meta = ((unsigned int)(d & 1023) << 18) | (unsigned int)src[e];
            float w = fminf(fmaxf(eattr[e], 0.f), 1.f);
            metaArr[slot] = meta;
            wHarr[slot] = __float2half(w);
        }
    }
}

// ======================= P4: two-pass fine sort (1024 thr, 4KB LDS) ==================
__global__ __launch_bounds__(1024) void p4_buildcsr(
    const int* __restrict__ bucketStart, const int* __restrict__ bucketTotal,
    const unsigned int* __restrict__ metaArr, const __half* __restrict__ wHarr,
    unsigned int* __restrict__ metaS, __half* __restrict__ wHs,
    int* __restrict__ rowptr) {
    __shared__ int hist[NPB];
    __shared__ int wsum[16];
    int b = blockIdx.x, tid = threadIdx.x;
    int start = bucketStart[b], count = bucketTotal[b];
    int nn = min(NPB, N_NODES - b * NPB);
    hist[tid] = 0;
    __syncthreads();
    // pass 1: histogram (coalesced global re-read)
    for (int i = tid; i < count; i += 1024)
        atomicAdd(&hist[metaArr[start + i] >> 18], 1);
    __syncthreads();
    // 1024-wide exclusive scan (each thread owns hist[tid])
    int v = hist[tid];
    int lane = tid & 63, wid = tid >> 6;
    int incl = v;
    #pragma unroll
    for (int o = 1; o < 64; o <<= 1) {
        int t = __shfl_up(incl, o, 64);
        if (lane >= o) incl += t;
    }
    if (lane == 63) wsum[wid] = incl;
    __syncthreads();
    int woff = 0;
    for (int w = 0; w < wid; ++w) woff += wsum[w];
    int excl = woff + incl - v;
    if (tid < nn) rowptr[b * NPB + tid] = start + excl;
    hist[tid] = excl;                            // becomes placement cursor
    __syncthreads();
    // pass 2: placement
    for (int i = tid; i < count; i += 1024) {
        unsigned int m = metaArr[start + i];
        int pos = start + atomicAdd(&hist[m >> 18], 1);
        metaS[pos] = m & 0x3FFFFu;
        wHs[pos] = wHarr[start + i];
    }
}

// ======================= agg1: gather-aggregate + ELU (16 lanes/node) =================
__global__ __launch_bounds__(256) void agg1_kernel(
    const unsigned int* __restrict__ metaS, const __half* __restrict__ wHs,
    const int* __restrict__ rowptr, const __half2* __restrict__ hbufH,
    __half* __restrict__ rbufH, const float* __restrict__ bias1) {
    int t = blockIdx.x * 256 + threadIdx.x;
    int n = t >> 4;
    if (n >= N_NODES) return;
    int c = t & 15;
    int beg = rowptr[n], end = rowptr[n + 1];
    float acc = 0.f;
    for (int p = beg; p < end; ++p) {
        int s = (int)metaS[p];
        float b1 = __half2float(wHs[p]);
        float2 h = __half22float2(hbufH[(size_t)s * HID + c]);
        acc += fmaf(b1, h.y - h.x, h.x);
    }
    float invd = 1.0f / fmaxf((float)(end - beg), 1.0f);
    float r = __half2float(rbufH[(size_t)n * HID + c]);
    float vv = fmaf(acc, invd, r) + bias1[c];
    float hv = vv > 0.f ? vv : expm1f(vv);
    rbufH[(size_t)n * HID + c] = __float2half(hv);
}

// ======================= node1b: tiny layer-2 transforms =======================
__global__ __launch_bounds__(256) void node1b_kernel(
    const __half* __restrict__ rbufH, const float* __restrict__ W2,
    const float* __restrict__ root2,
    __half2* __restrict__ h2buf, float* __restrict__ r2buf) {
    int n = blockIdx.x * 256 + threadIdx.x;
    if (n >= N_NODES) return;
    float h[HID];
    #pragma unroll
    for (int k = 0; k < HID; ++k) h[k] = __half2float(rbufH[(size_t)n * HID + k]);
    float o0[NCLS], o1[NCLS], orr[NCLS];
    #pragma unroll
    for (int j = 0; j < NCLS; ++j) { o0[j] = 0.f; o1[j] = 0.f; orr[j] = 0.f; }
    const float* __restrict__ W2b = W2 + HID * NCLS;
    #pragma unroll
    for (int k = 0; k < HID; ++k) {
        #pragma unroll
        for (int j = 0; j < NCLS; ++j) {
            o0[j]  = fmaf(h[k], W2 [k * NCLS + j], o0[j]);
            o1[j]  = fmaf(h[k], W2b[k * NCLS + j], o1[j]);
            orr[j] = fmaf(h[k], root2[k * NCLS + j], orr[j]);
        }
    }
    __half2* hb = h2buf + (size_t)n * 8;
    float*   r2 = r2buf + (size_t)n * 8;
    #pragma unroll
    for (int j = 0; j < NCLS; ++j) {
        hb[j] = __floats2half2_rn(o0[j], o1[j]);
        r2[j] = orr[j];
    }
    hb[7] = __floats2half2_rn(0.f, 0.f);
    r2[7] = 0.f;
}

// ======================= agg2: gather-aggregate + log_softmax (8 lanes/node) ==========
__global__ __launch_bounds__(256) void agg2_kernel(
    const unsigned int* __restrict__ metaS, const __half* __restrict__ wHs,
    const int* __restrict__ rowptr, const __half2* __restrict__ h2buf,
    const float* __restrict__ r2buf, const float* __restrict__ bias2,
    float* __restrict__ out) {
    int t = blockIdx.x * 256 + threadIdx.x;
    int n = t >> 3;
    if (n >= N_NODES) return;
    int j = t & 7;
    int beg = rowptr[n], end = rowptr[n + 1];
    float acc = 0.f;
    for (int p = beg; p < end; ++p) {
        int s = (int)metaS[p];
        float b1 = __half2float(wHs[p]);
        float2 m = __half22float2(h2buf[(size_t)s * 8 + j]);
        acc += fmaf(b1, m.y - m.x, m.x);
    }
    float invd = 1.0f / fmaxf((float)(end - beg), 1.0f);
    float v = fmaf(acc, invd, r2buf[(size_t)n * 8 + j]) + ((j < NCLS) ? bias2[j] : 0.f);
    if (j == NCLS) v = -INFINITY;
    float mx = v;
    mx = fmaxf(mx, __shfl_xor(mx, 1, 8));
    mx = fmaxf(mx, __shfl_xor(mx, 2, 8));
    mx = fmaxf(mx, __shfl_xor(mx, 4, 8));
    float ex = expf(v - mx);
    float sm = ex;
    sm += __shfl_xor(sm, 1, 8);
    sm += __shfl_xor(sm, 2, 8);
    sm += __shfl_xor(sm, 4, 8);
    float lse = mx + logf(sm);
    if (j < NCLS) out[(size_t)n * NCLS + j] = v - lse;
}

extern "C" void kernel_launch(void* const* d_in, const int* in_sizes, int n_in,
                              void* d_out, int out_size, void* d_ws, size_t ws_size,
                              hipStream_t stream) {
    const float* x     = (const float*)d_in[0];
    const float* eattr = (const float*)d_in[1];
    const int*   src   = (const int*)d_in[2];
    const int*   dst   = (const int*)d_in[3];
    const float* W1    = (const float*)d_in[4];
    const float* root1 = (const float*)d_in[5];
    const float* bias1 = (const float*)d_in[6];
    const float* W2    = (const float*)d_in[7];
    const float* root2 = (const float*)d_in[8];
    const float* bias2 = (const float*)d_in[9];
    float* out = (float*)d_out;

    // ---------- workspace layout (~98 MB) ----------
    char* wp = (char*)d_ws;
    unsigned int* metaArr = (unsigned int*)wp;  wp += (size_t)N_EDGES * 4;           // 25.6 MB
    __half*       wHarr   = (__half*)wp;        wp += (size_t)N_EDGES * 2;           // 12.8 MB
    unsigned int* metaS   = (unsigned int*)wp;  wp += (size_t)N_EDGES * 4;           // 25.6 MB
    __half*       wHs     = (__half*)wp;        wp += (size_t)N_EDGES * 2;           // 12.8 MB
    int* blockOff    = (int*)wp;                wp += (size_t)NBUCKET * NBLKE * 4;   // 306 KB
    int* bucketTotal = (int*)wp;                wp += 1024 * 4;
    int* bucketStart = (int*)wp;                wp += 1024 * 4;
    int* rowptr      = (int*)wp;                wp += (size_t)(N_NODES + 4) * 4;     // 0.8 MB
    __half* Bf       = (__half*)wp;             wp += (size_t)3 * 16 * 64 * 8 * 2;   // 48 KB
    __half2* hbufH   = (__half2*)wp;            wp += (size_t)N_NODES * HID * 4;     // 12.8 MB
    __half*  rbufH   = (__half*)wp;             wp += (size_t)N_NODES * HID * 2;     // 6.4 MB
    // aliases: hbufH region is dead after agg1
    __half2* h2buf = hbufH;                                          // N*8 half2
    float*   r2buf = (float*)(hbufH + (size_t)N_NODES * 8);          // N*8 f32

    const int node_blocks = (N_NODES + 255) / 256;  // 782

    hipLaunchKernelGGL(packB_kernel, dim3((3 * 16 * 64 + 255) / 256), dim3(256), 0, stream,
                       W1, root1, Bf);
    hipLaunchKernelGGL(gemm1_kernel, dim3(N_NODES / GROWS), dim3(256), 0, stream,
                       x, Bf, hbufH, rbufH);
    hipLaunchKernelGGL(p1_bincount, dim3(NBLKE), dim3(256), 0, stream, dst, blockOff);
    hipLaunchKernelGGL(p2a_kernel, dim3(NBUCKET), dim3(256), 0, stream,
                       blockOff, bucketTotal);
    hipLaunchKernelGGL(p2b_kernel, dim3(1), dim3(256), 0, stream,
                       bucketTotal, bucketStart, rowptr);
    hipLaunchKernelGGL(p3_binscatter, dim3(NBLKE), dim3(256), 0, stream,
                       dst, src, eattr, blockOff, bucketStart, metaArr, wHarr);
    hipLaunchKernelGGL(p4_buildcsr, dim3(NBUCKET), dim3(1024), 0, stream,
                       bucketStart, bucketTotal, metaArr, wHarr, metaS, wHs, rowptr);
    hipLaunchKernelGGL(agg1_kernel, dim3((N_NODES * 16 + 255) / 256), dim3(256), 0, stream,
                       metaS, wHs, rowptr, hbufH, rbufH, bias1);
    hipLaunchKernelGGL(node1b_kernel, dim3(node_blocks), dim3(256), 0, stream,
                       rbufH, W2, root2, h2buf, r2buf);
    hipLaunchKernelGGL(agg2_kernel, dim3((N_NODES * 8 + 255) / 256), dim3(256), 0, stream,
                       metaS, wHs, rowptr, h2buf, r2buf, bias2, out);
}

// Round 14
// 606.297 us; speedup vs baseline: 2.2520x; 1.1957x over previous
//
#include <hip/hip_runtime.h>
#include <hip/hip_fp16.h>
#include <math.h>

#define N_NODES 200000
#define N_EDGES 6400000
#define F_INF   512
#define HID     16
#define NCLS    7

#define NPB      1024                              // nodes per bucket
#define NBUCKET  ((N_NODES + NPB - 1) / NPB)       // 196
#define CHUNK    16384
#define NBLKE    ((N_EDGES + CHUNK - 1) / CHUNK)   // 391

// ---- gemm1 (MFMA) geometry ----
#define GROWS 64     // rows per block (4 waves x 16)
#define KCHG  256    // K-chunk in fp32 elems (2 chunks of 256 = 512)
#define ASTR  264    // LDS row stride in halves (528B = 4 banks mod 32 -> uniform)

typedef _Float16 f16x8 __attribute__((ext_vector_type(8)));
typedef float    f32x4 __attribute__((ext_vector_type(4)));

// ======================= pack (W1[0]|W1[1]|root1) into MFMA B-fragment order ========
__global__ __launch_bounds__(256) void packB_kernel(
    const float* __restrict__ W1, const float* __restrict__ root1,
    __half* __restrict__ Bf) {
    int tt = blockIdx.x * 256 + threadIdx.x;    // 3*16*64 = 3072
    if (tt >= 3 * 16 * 64) return;
    int lane = tt & 63, kk = (tt >> 6) & 15, t = tt >> 10;
    int col = lane & 15;
    int kbase = kk * 32 + (lane >> 4) * 8;
    const float* __restrict__ srcm = (t == 0) ? W1
                                   : (t == 1) ? (W1 + F_INF * HID) : root1;
    #pragma unroll
    for (int j = 0; j < 8; ++j)
        Bf[(size_t)tt * 8 + j] = __float2half(srcm[(kbase + j) * HID + col]);
}

// ======================= layer 1 GEMM via MFMA =======================
__global__ __launch_bounds__(256) void gemm1_kernel(
    const float* __restrict__ x, const __half* __restrict__ Bf,
    __half2* __restrict__ hbufH, __half* __restrict__ rbufH) {
    __shared__ __half As[GROWS * ASTR];          // 33792 B
    int tid = threadIdx.x;
    int l = tid & 63, w = tid >> 6;
    int rowBase = blockIdx.x * GROWS;

    f32x4 acc0 = {0.f, 0.f, 0.f, 0.f};
    f32x4 acc1 = {0.f, 0.f, 0.f, 0.f};
    f32x4 acc2 = {0.f, 0.f, 0.f, 0.f};

    const __half* __restrict__ Arow = &As[(w * 16 + (l & 15)) * ASTR + (l >> 4) * 8];

    for (int ch = 0; ch < F_INF / KCHG; ++ch) {  // 2 chunks
        __syncthreads();
        #pragma unroll
        for (int j = 0; j < 16; ++j) {
            int row = w * 16 + j;
            float4 v = *(const float4*)(x + (size_t)(rowBase + row) * F_INF
                                          + ch * KCHG + l * 4);
            union { __half2 h2[2]; float2 f2; } u;
            u.h2[0] = __floats2half2_rn(v.x, v.y);
            u.h2[1] = __floats2half2_rn(v.z, v.w);
            *(float2*)(&As[row * ASTR + l * 4]) = u.f2;
        }
        __syncthreads();
        #pragma unroll
        for (int kkl = 0; kkl < 8; ++kkl) {
            f16x8 a = *(const f16x8*)(Arow + kkl * 32);
            int kkg = ch * 8 + kkl;
            const __half* bp = Bf + ((size_t)kkg * 64 + l) * 8;
            f16x8 b0 = *(const f16x8*)(bp);
            f16x8 b1 = *(const f16x8*)(bp + 16 * 64 * 8);
            f16x8 b2 = *(const f16x8*)(bp + 2 * 16 * 64 * 8);
            acc0 = __builtin_amdgcn_mfma_f32_16x16x32_f16(a, b0, acc0, 0, 0, 0);
            acc1 = __builtin_amdgcn_mfma_f32_16x16x32_f16(a, b1, acc1, 0, 0, 0);
            acc2 = __builtin_amdgcn_mfma_f32_16x16x32_f16(a, b2, acc2, 0, 0, 0);
        }
    }
    int c = l & 15;
    int rbase = rowBase + w * 16 + (l >> 4) * 4;
    #pragma unroll
    for (int r = 0; r < 4; ++r) {
        int n = rbase + r;
        hbufH[(size_t)n * HID + c] = __floats2half2_rn(acc0[r], acc1[r]);
        rbufH[(size_t)n * HID + c] = __float2half(acc2[r]);
    }
}

// ======================= P1: per-block bucket histogram (4 sub-hists) ================
__global__ __launch_bounds__(256) void p1_bincount(const int* __restrict__ dst,
                                                   int* __restrict__ blockOff) {
    __shared__ int hist[4][NBUCKET];
    int tid = threadIdx.x, w = tid >> 6;
    for (int i = tid; i < 4 * NBUCKET; i += 256) hist[i / NBUCKET][i % NBUCKET] = 0;
    __syncthreads();
    size_t base = (size_t)blockIdx.x * CHUNK;
    for (int i = 0; i < CHUNK / 256; ++i) {
        size_t e = base + (size_t)i * 256 + tid;
        if (e < N_EDGES) atomicAdd(&hist[w][dst[e] >> 10], 1);
    }
    __syncthreads();
    for (int i = tid; i < NBUCKET; i += 256)
        blockOff[(size_t)i * NBLKE + blockIdx.x] =
            hist[0][i] + hist[1][i] + hist[2][i] + hist[3][i];
}

// ======================= P2a: per-bucket scan over blocks =======================
__global__ __launch_bounds__(256) void p2a_kernel(int* __restrict__ blockOff,
                                                  int* __restrict__ bucketTotal) {
    __shared__ int wsum[4];
    int b = blockIdx.x, tid = threadIdx.x;
    size_t rowb = (size_t)b * NBLKE;
    int i0 = tid * 2, i1 = i0 + 1;
    int v0 = (i0 < NBLKE) ? blockOff[rowb + i0] : 0;
    int v1 = (i1 < NBLKE) ? blockOff[rowb + i1] : 0;
    int s = v0 + v1;
    int lane = tid & 63, wid = tid >> 6;
    int incl = s;
    #pragma unroll
    for (int o = 1; o < 64; o <<= 1) {
        int t = __shfl_up(incl, o, 64);
        if (lane >= o) incl += t;
    }
    if (lane == 63) wsum[wid] = incl;
    __syncthreads();
    int woff = 0;
    for (int w = 0; w < wid; ++w) woff += wsum[w];
    int excl = woff + incl - s;
    if (i0 < NBLKE) blockOff[rowb + i0] = excl;
    if (i1 < NBLKE) blockOff[rowb + i1] = excl + v0;
    if (tid == 255) bucketTotal[b] = woff + incl;
}

// ======================= P2b: scan bucket totals -> bucketStart =======================
__global__ __launch_bounds__(256) void p2b_kernel(const int* __restrict__ bucketTotal,
                                                  int* __restrict__ bucketStart,
                                                  int* __restrict__ rowptr) {
    __shared__ int wsum[4];
    int tid = threadIdx.x;
    int base = tid * 4;
    int v[4]; int s = 0;
    #pragma unroll
    for (int q = 0; q < 4; ++q) {
        int idx = base + q;
        v[q] = (idx < NBUCKET) ? bucketTotal[idx] : 0;
        s += v[q];
    }
    int lane = tid & 63, wid = tid >> 6;
    int incl = s;
    #pragma unroll
    for (int o = 1; o < 64; o <<= 1) {
        int t = __shfl_up(incl, o, 64);
        if (lane >= o) incl += t;
    }
    if (lane == 63) wsum[wid] = incl;
    __syncthreads();
    int woff = 0;
    for (int w = 0; w < wid; ++w) woff += wsum[w];
    int run = woff + incl - s;
    #pragma unroll
    for (int q = 0; q < 4; ++q) {
        int idx = base + q;
        if (idx < NBUCKET) bucketStart[idx] = run;
        run += v[q];
    }
    if (tid == 0) rowptr[N_NODES] = N_EDGES;
}

// ======================= P3: binned scatter of payload (196 buckets) =================
// meta = (local[10b] << 18) | src[18b]
__global__ __launch_bounds__(256) void p3_binscatter(
    const int* __restrict__ dst, const int* __restrict__ src,
    const float* __restrict__ eattr,
    const int* __restrict__ blockOff, const int* __restrict__ bucketStart,
    unsigned int* __restrict__ metaArr, __half* __restrict__ wHarr) {
    __shared__ int cur[NBUCKET];
    int tid = threadIdx.x;
    for (int i = tid; i < NBUCKET; i += 256)
        cur[i] = bucketStart[i] + blockOff[(size_t)i * NBLKE + blockIdx.x];
    __syncthreads();
    size_t base = (size_t)blockIdx.x * CHUNK;
    for (int i = 0; i < CHUNK / 256; ++i) {
        size_t e = base + (size_t)i * 256 + tid;
        if (e < N_EDGES) {
            int d = dst[e];
            int b = d >> 10;
            int slot = atomicAdd(&cur[b], 1);
            unsigned int meta = ((unsigned int)(d & 1023) << 18) | (unsigned int)src[e];
            float w = fminf(fmaxf(eattr[e], 0.f), 1.f);
            metaArr[slot] = meta;
            wHarr[slot] = __float2half(w);
        }
    }
}

// ======================= P4: two-pass fine sort (1024 thr, 4KB LDS) ==================
__global__ __launch_bounds__(1024) void p4_buildcsr(
    const int* __restrict__ bucketStart, const int* __restrict__ bucketTotal,
    const unsigned int* __restrict__ metaArr, const __half* __restrict__ wHarr,
    unsigned int* __restrict__ metaS, __half* __restrict__ wHs,
    int* __restrict__ rowptr) {
    __shared__ int hist[NPB];
    __shared__ int wsum[16];
    int b = blockIdx.x, tid = threadIdx.x;
    int start = bucketStart[b], count = bucketTotal[b];
    int nn = min(NPB, N_NODES - b * NPB);
    hist[tid] = 0;
    __syncthreads();
    // pass 1: histogram (coalesced global re-read)
    for (int i = tid; i < count; i += 1024)
        atomicAdd(&hist[metaArr[start + i] >> 18], 1);
    __syncthreads();
    // 1024-wide exclusive scan (each thread owns hist[tid])
    int v = hist[tid];
    int lane = tid & 63, wid = tid >> 6;
    int incl = v;
    #pragma unroll
    for (int o = 1; o < 64; o <<= 1) {
        int t = __shfl_up(incl, o, 64);
        if (lane >= o) incl += t;
    }
    if (lane == 63) wsum[wid] = incl;
    __syncthreads();
    int woff = 0;
    for (int w = 0; w < wid; ++w) woff += wsum[w];
    int excl = woff + incl - v;
    if (tid < nn) rowptr[b * NPB + tid] = start + excl;
    hist[tid] = excl;                            // becomes placement cursor
    __syncthreads();
    // pass 2: placement
    for (int i = tid; i < count; i += 1024) {
        unsigned int m = metaArr[start + i];
        int pos = start + atomicAdd(&hist[m >> 18], 1);
        metaS[pos] = m & 0x3FFFFu;
        wHs[pos] = wHarr[start + i];
    }
}

// ======================= agg1: gather-aggregate + ELU (16 lanes/node, 4x unroll) ======
__global__ __launch_bounds__(256) void agg1_kernel(
    const unsigned int* __restrict__ metaS, const __half* __restrict__ wHs,
    const int* __restrict__ rowptr, const __half2* __restrict__ hbufH,
    __half* __restrict__ rbufH, const float* __restrict__ bias1) {
    int t = blockIdx.x * 256 + threadIdx.x;
    int n = t >> 4;
    if (n >= N_NODES) return;
    int c = t & 15;
    int beg = rowptr[n], end = rowptr[n + 1];
    float acc = 0.f;
    int p = beg;
    for (; p + 4 <= end; p += 4) {
        unsigned int s0 = metaS[p + 0], s1 = metaS[p + 1];
        unsigned int s2 = metaS[p + 2], s3 = metaS[p + 3];
        float w0 = __half2float(wHs[p + 0]);
        float w1 = __half2float(wHs[p + 1]);
        float w2 = __half2float(wHs[p + 2]);
        float w3 = __half2float(wHs[p + 3]);
        float2 h0 = __half22float2(hbufH[(size_t)s0 * HID + c]);
        float2 h1 = __half22float2(hbufH[(size_t)s1 * HID + c]);
        float2 h2 = __half22float2(hbufH[(size_t)s2 * HID + c]);
        float2 h3 = __half22float2(hbufH[(size_t)s3 * HID + c]);
        acc += fmaf(w0, h0.y - h0.x, h0.x);
        acc += fmaf(w1, h1.y - h1.x, h1.x);
        acc += fmaf(w2, h2.y - h2.x, h2.x);
        acc += fmaf(w3, h3.y - h3.x, h3.x);
    }
    for (; p < end; ++p) {
        unsigned int s = metaS[p];
        float w = __half2float(wHs[p]);
        float2 h = __half22float2(hbufH[(size_t)s * HID + c]);
        acc += fmaf(w, h.y - h.x, h.x);
    }
    float invd = 1.0f / fmaxf((float)(end - beg), 1.0f);
    float r = __half2float(rbufH[(size_t)n * HID + c]);
    float vv = fmaf(acc, invd, r) + bias1[c];
    float hv = vv > 0.f ? vv : expm1f(vv);
    rbufH[(size_t)n * HID + c] = __float2half(hv);
}

// ======================= node1b: tiny layer-2 transforms =======================
__global__ __launch_bounds__(256) void node1b_kernel(
    const __half* __restrict__ rbufH, const float* __restrict__ W2,
    const float* __restrict__ root2,
    __half2* __restrict__ h2buf, float* __restrict__ r2buf) {
    int n = blockIdx.x * 256 + threadIdx.x;
    if (n >= N_NODES) return;
    float h[HID];
    #pragma unroll
    for (int k = 0; k < HID; ++k) h[k] = __half2float(rbufH[(size_t)n * HID + k]);
    float o0[NCLS], o1[NCLS], orr[NCLS];
    #pragma unroll
    for (int j = 0; j < NCLS; ++j) { o0[j] = 0.f; o1[j] = 0.f; orr[j] = 0.f; }
    const float* __restrict__ W2b = W2 + HID * NCLS;
    #pragma unroll
    for (int k = 0; k < HID; ++k) {
        #pragma unroll
        for (int j = 0; j < NCLS; ++j) {
            o0[j]  = fmaf(h[k], W2 [k * NCLS + j], o0[j]);
            o1[j]  = fmaf(h[k], W2b[k * NCLS + j], o1[j]);
            orr[j] = fmaf(h[k], root2[k * NCLS + j], orr[j]);
        }
    }
    __half2* hb = h2buf + (size_t)n * 8;
    float*   r2 = r2buf + (size_t)n * 8;
    #pragma unroll
    for (int j = 0; j < NCLS; ++j) {
        hb[j] = __floats2half2_rn(o0[j], o1[j]);
        r2[j] = orr[j];
    }
    hb[7] = __floats2half2_rn(0.f, 0.f);
    r2[7] = 0.f;
}

// ======================= agg2: gather-aggregate + log_softmax (8 lanes/node, 4x) ======
__global__ __launch_bounds__(256) void agg2_kernel(
    const unsigned int* __restrict__ metaS, const __half* __restrict__ wHs,
    const int* __restrict__ rowptr, const __half2* __restrict__ h2buf,
    const float* __restrict__ r2buf, const float* __restrict__ bias2,
    float* __restrict__ out) {
    int t = blockIdx.x * 256 + threadIdx.x;
    int n = t >> 3;
    if (n >= N_NODES) return;
    int j = t & 7;
    int beg = rowptr[n], end = rowptr[n + 1];
    float acc = 0.f;
    int p = beg;
    for (; p + 4 <= end; p += 4) {
        unsigned int s0 = metaS[p + 0], s1 = metaS[p + 1];
        unsigned int s2 = metaS[p + 2], s3 = metaS[p + 3];
        float w0 = __half2float(wHs[p + 0]);
        float w1 = __half2float(wHs[p + 1]);
        float w2 = __half2float(wHs[p + 2]);
        float w3 = __half2float(wHs[p + 3]);
        float2 m0 = __half22float2(h2buf[(size_t)s0 * 8 + j]);
        float2 m1 = __half22float2(h2buf[(size_t)s1 * 8 + j]);
        float2 m2 = __half22float2(h2buf[(size_t)s2 * 8 + j]);
        float2 m3 = __half22float2(h2buf[(size_t)s3 * 8 + j]);
        acc += fmaf(w0, m0.y - m0.x, m0.x);
        acc += fmaf(w1, m1.y - m1.x, m1.x);
        acc += fmaf(w2, m2.y - m2.x, m2.x);
        acc += fmaf(w3, m3.y - m3.x, m3.x);
    }
    for (; p < end; ++p) {
        unsigned int s = metaS[p];
        float w = __half2float(wHs[p]);
        float2 m = __half22float2(h2buf[(size_t)s * 8 + j]);
        acc += fmaf(w, m.y - m.x, m.x);
    }
    float invd = 1.0f / fmaxf((float)(end - beg), 1.0f);
    float v = fmaf(acc, invd, r2buf[(size_t)n * 8 + j]) + ((j < NCLS) ? bias2[j] : 0.f);
    if (j == NCLS) v = -INFINITY;
    float mx = v;
    mx = fmaxf(mx, __shfl_xor(mx, 1, 8));
    mx = fmaxf(mx, __shfl_xor(mx, 2, 8));
    mx = fmaxf(mx, __shfl_xor(mx, 4, 8));
    float ex = expf(v - mx);
    float sm = ex;
    sm += __shfl_xor(sm, 1, 8);
    sm += __shfl_xor(sm, 2, 8);
    sm += __shfl_xor(sm, 4, 8);
    float lse = mx + logf(sm);
    if (j < NCLS) out[(size_t)n * NCLS + j] = v - lse;
}

extern "C" void kernel_launch(void* const* d_in, const int* in_sizes, int n_in,
                              void* d_out, int out_size, void* d_ws, size_t ws_size,
                              hipStream_t stream) {
    const float* x     = (const float*)d_in[0];
    const float* eattr = (const float*)d_in[1];
    const int*   src   = (const int*)d_in[2];
    const int*   dst   = (const int*)d_in[3];
    const float* W1    = (const float*)d_in[4];
    const float* root1 = (const float*)d_in[5];
    const float* bias1 = (const float*)d_in[6];
    const float* W2    = (const float*)d_in[7];
    const float* root2 = (const float*)d_in[8];
    const float* bias2 = (const float*)d_in[9];
    float* out = (float*)d_out;

    // ---------- workspace layout (~98 MB) ----------
    char* wp = (char*)d_ws;
    unsigned int* metaArr = (unsigned int*)wp;  wp += (size_t)N_EDGES * 4;           // 25.6 MB
    __half*       wHarr   = (__half*)wp;        wp += (size_t)N_EDGES * 2;           // 12.8 MB
    unsigned int* metaS   = (unsigned int*)wp;  wp += (size_t)N_EDGES * 4;           // 25.6 MB
    __half*       wHs     = (__half*)wp;        wp += (size_t)N_EDGES * 2;           // 12.8 MB
    int* blockOff    = (int*)wp;                wp += (size_t)NBUCKET * NBLKE * 4;   // 306 KB
    int* bucketTotal = (int*)wp;                wp += 1024 * 4;
    int* bucketStart = (int*)wp;                wp += 1024 * 4;
    int* rowptr      = (int*)wp;                wp += (size_t)(N_NODES + 4) * 4;     // 0.8 MB
    __half* Bf       = (__half*)wp;             wp += (size_t)3 * 16 * 64 * 8 * 2;   // 48 KB
    __half2* hbufH   = (__half2*)wp;            wp += (size_t)N_NODES * HID * 4;     // 12.8 MB
    __half*  rbufH   = (__half*)wp;             wp += (size_t)N_NODES * HID * 2;     // 6.4 MB
    // aliases: hbufH region is dead after agg1
    __half2* h2buf = hbufH;                                          // N*8 half2
    float*   r2buf = (float*)(hbufH + (size_t)N_NODES * 8);          // N*8 f32

    const int node_blocks = (N_NODES + 255) / 256;  // 782

    hipLaunchKernelGGL(packB_kernel, dim3((3 * 16 * 64 + 255) / 256), dim3(256), 0, stream,
                       W1, root1, Bf);
    hipLaunchKernelGGL(gemm1_kernel, dim3(N_NODES / GROWS), dim3(256), 0, stream,
                       x, Bf, hbufH, rbufH);
    hipLaunchKernelGGL(p1_bincount, dim3(NBLKE), dim3(256), 0, stream, dst, blockOff);
    hipLaunchKernelGGL(p2a_kernel, dim3(NBUCKET), dim3(256), 0, stream,
                       blockOff, bucketTotal);
    hipLaunchKernelGGL(p2b_kernel, dim3(1), dim3(256), 0, stream,
                       bucketTotal, bucketStart, rowptr);
    hipLaunchKernelGGL(p3_binscatter, dim3(NBLKE), dim3(256), 0, stream,
                       dst, src, eattr, blockOff, bucketStart, metaArr, wHarr);
    hipLaunchKernelGGL(p4_buildcsr, dim3(NBUCKET), dim3(1024), 0, stream,
                       bucketStart, bucketTotal, metaArr, wHarr, metaS, wHs, rowptr);
    hipLaunchKernelGGL(agg1_kernel, dim3((N_NODES * 16 + 255) / 256), dim3(256), 0, stream,
                       metaS, wHs, rowptr, hbufH, rbufH, bias1);
    hipLaunchKernelGGL(node1b_kernel, dim3(node_blocks), dim3(256), 0, stream,
                       rbufH, W2, root2, h2buf, r2buf);
    hipLaunchKernelGGL(agg2_kernel, dim3((N_NODES * 8 + 255) / 256), dim3(256), 0, stream,
                       metaS, wHs, rowptr, h2buf, r2buf, bias2, out);
}

// Round 16
// 567.835 us; speedup vs baseline: 2.4046x; 1.0677x over previous
//
#include <hip/hip_runtime.h>
#include <hip/hip_fp16.h>
#include <math.h>

#define N_NODES 200000
#define N_EDGES 6400000
#define F_INF   512
#define HID     16
#define NCLS    7

#define NPB      1024                              // nodes per bucket
#define NBUCKET  ((N_NODES + NPB - 1) / NPB)       // 196
#define CHUNK    16384
#define NBLKE    ((N_EDGES + CHUNK - 1) / CHUNK)   // 391

// ---- gemm1 (MFMA) geometry ----
#define GROWS 64     // rows per block (4 waves x 16)
#define KCHG  256    // K-chunk in fp32 elems (2 chunks of 256 = 512)
#define ASTR  264    // LDS row stride in halves (528B = 4 banks mod 32 -> uniform)

typedef _Float16 f16x8 __attribute__((ext_vector_type(8)));
typedef float    f32x4 __attribute__((ext_vector_type(4)));

// ======================= pack (W1[0]|W1[1]|root1) into MFMA B-fragment order ========
__global__ __launch_bounds__(256) void packB_kernel(
    const float* __restrict__ W1, const float* __restrict__ root1,
    __half* __restrict__ Bf) {
    int tt = blockIdx.x * 256 + threadIdx.x;    // 3*16*64 = 3072
    if (tt >= 3 * 16 * 64) return;
    int lane = tt & 63, kk = (tt >> 6) & 15, t = tt >> 10;
    int col = lane & 15;
    int kbase = kk * 32 + (lane >> 4) * 8;
    const float* __restrict__ srcm = (t == 0) ? W1
                                   : (t == 1) ? (W1 + F_INF * HID) : root1;
    #pragma unroll
    for (int j = 0; j < 8; ++j)
        Bf[(size_t)tt * 8 + j] = __float2half(srcm[(kbase + j) * HID + col]);
}

// ======================= layer 1 GEMM via MFMA =======================
__global__ __launch_bounds__(256) void gemm1_kernel(
    const float* __restrict__ x, const __half* __restrict__ Bf,
    __half2* __restrict__ hbufH, __half* __restrict__ rbufH) {
    __shared__ __half As[GROWS * ASTR];          // 33792 B
    int tid = threadIdx.x;
    int l = tid & 63, w = tid >> 6;
    int rowBase = blockIdx.x * GROWS;

    f32x4 acc0 = {0.f, 0.f, 0.f, 0.f};
    f32x4 acc1 = {0.f, 0.f, 0.f, 0.f};
    f32x4 acc2 = {0.f, 0.f, 0.f, 0.f};

    const __half* __restrict__ Arow = &As[(w * 16 + (l & 15)) * ASTR + (l >> 4) * 8];

    for (int ch = 0; ch < F_INF / KCHG; ++ch) {  // 2 chunks
        __syncthreads();
        #pragma unroll
        for (int j = 0; j < 16; ++j) {
            int row = w * 16 + j;
            float4 v = *(const float4*)(x + (size_t)(rowBase + row) * F_INF
                                          + ch * KCHG + l * 4);
            union { __half2 h2[2]; float2 f2; } u;
            u.h2[0] = __floats2half2_rn(v.x, v.y);
            u.h2[1] = __floats2half2_rn(v.z, v.w);
            *(float2*)(&As[row * ASTR + l * 4]) = u.f2;
        }
        __syncthreads();
        #pragma unroll
        for (int kkl = 0; kkl < 8; ++kkl) {
            f16x8 a = *(const f16x8*)(Arow + kkl * 32);
            int kkg = ch * 8 + kkl;
            const __half* bp = Bf + ((size_t)kkg * 64 + l) * 8;
            f16x8 b0 = *(const f16x8*)(bp);
            f16x8 b1 = *(const f16x8*)(bp + 16 * 64 * 8);
            f16x8 b2 = *(const f16x8*)(bp + 2 * 16 * 64 * 8);
            acc0 = __builtin_amdgcn_mfma_f32_16x16x32_f16(a, b0, acc0, 0, 0, 0);
            acc1 = __builtin_amdgcn_mfma_f32_16x16x32_f16(a, b1, acc1, 0, 0, 0);
            acc2 = __builtin_amdgcn_mfma_f32_16x16x32_f16(a, b2, acc2, 0, 0, 0);
        }
    }
    int c = l & 15;
    int rbase = rowBase + w * 16 + (l >> 4) * 4;
    #pragma unroll
    for (int r = 0; r < 4; ++r) {
        int n = rbase + r;
        hbufH[(size_t)n * HID + c] = __floats2half2_rn(acc0[r], acc1[r]);
        rbufH[(size_t)n * HID + c] = __float2half(acc2[r]);
    }
}

// ======================= P1: per-block bucket histogram (4 sub-hists) ================
__global__ __launch_bounds__(256) void p1_bincount(const int* __restrict__ dst,
                                                   int* __restrict__ blockOff) {
    __shared__ int hist[4][NBUCKET];
    int tid = threadIdx.x, w = tid >> 6;
    for (int i = tid; i < 4 * NBUCKET; i += 256) hist[i / NBUCKET][i % NBUCKET] = 0;
    __syncthreads();
    size_t base = (size_t)blockIdx.x * CHUNK;
    for (int i = 0; i < CHUNK / 256; ++i) {
        size_t e = base + (size_t)i * 256 + tid;
        if (e < N_EDGES) atomicAdd(&hist[w][dst[e] >> 10], 1);
    }
    __syncthreads();
    for (int i = tid; i < NBUCKET; i += 256)
        blockOff[(size_t)i * NBLKE + blockIdx.x] =
            hist[0][i] + hist[1][i] + hist[2][i] + hist[3][i];
}

// ======================= P2a: per-bucket scan over blocks =======================
__global__ __launch_bounds__(256) void p2a_kernel(int* __restrict__ blockOff,
                                                  int* __restrict__ bucketTotal) {
    __shared__ int wsum[4];
    int b = blockIdx.x, tid = threadIdx.x;
    size_t rowb = (size_t)b * NBLKE;
    int i0 = tid * 2, i1 = i0 + 1;
    int v0 = (i0 < NBLKE) ? blockOff[rowb + i0] : 0;
    int v1 = (i1 < NBLKE) ? blockOff[rowb + i1] : 0;
    int s = v0 + v1;
    int lane = tid & 63, wid = tid >> 6;
    int incl = s;
    #pragma unroll
    for (int o = 1; o < 64; o <<= 1) {
        int t = __shfl_up(incl, o, 64);
        if (lane >= o) incl += t;
    }
    if (lane == 63) wsum[wid] = incl;
    __syncthreads();
    int woff = 0;
    for (int w = 0; w < wid; ++w) woff += wsum[w];
    int excl = woff + incl - s;
    if (i0 < NBLKE) blockOff[rowb + i0] = excl;
    if (i1 < NBLKE) blockOff[rowb + i1] = excl + v0;
    if (tid == 255) bucketTotal[b] = woff + incl;
}

// ======================= P2b: scan bucket totals -> bucketStart =======================
__global__ __launch_bounds__(256) void p2b_kernel(const int* __restrict__ bucketTotal,
                                                  int* __restrict__ bucketStart,
                                                  int* __restrict__ rowptr) {
    __shared__ int wsum[4];
    int tid = threadIdx.x;
    int base = tid * 4;
    int v[4]; int s = 0;
    #pragma unroll
    for (int q = 0; q < 4; ++q) {
        int idx = base + q;
        v[q] = (idx < NBUCKET) ? bucketTotal[idx] : 0;
        s += v[q];
    }
    int lane = tid & 63, wid = tid >> 6;
    int incl = s;
    #pragma unroll
    for (int o = 1; o < 64; o <<= 1) {
        int t = __shfl_up(incl, o, 64);
        if (lane >= o) incl += t;
    }
    if (lane == 63) wsum[wid] = incl;
    __syncthreads();
    int woff = 0;
    for (int w = 0; w < wid; ++w) woff += wsum[w];
    int run = woff + incl - s;
    #pragma unroll
    for (int q = 0; q < 4; ++q) {
        int idx = base + q;
        if (idx < NBUCKET) bucketStart[idx] = run;
        run += v[q];
    }
    if (tid == 0) rowptr[N_NODES] = N_EDGES;
}

// ======================= P3: binned scatter of payload (196 buckets) =================
// meta = (local[10b] << 18) | src[18b]
__global__ __launch_bounds__(256) void p3_binscatter(
    const int* __restrict__ dst, const int* __restrict__ src,
    const float* __restrict__ eattr,
    const int* __restrict__ blockOff, const int* __restrict__ bucketStart,
    unsigned int* __restrict__ metaArr, __half* __restrict__ wHarr) {
    __shared__ int cur[NBUCKET];
    int tid = threadIdx.x;
    for (int i = tid; i < NBUCKET; i += 256)
        cur[i] = bucketStart[i] + blockOff[(size_t)i * NBLKE + blockIdx.x];
    __syncthreads();
    size_t base = (size_t)blockIdx.x * CHUNK;
    for (int i = 0; i < CHUNK / 256; ++i) {
        size_t e = base + (size_t)i * 256 + tid;
        if (e < N_EDGES) {
            int d = dst[e];
            int b = d >> 10;
            int slot = atomicAdd(&cur[b], 1);
            unsigned int meta = ((unsigned int)(d & 1023) << 18) | (unsigned int)src[e];
            float w = fminf(fmaxf(eattr[e], 0.f), 1.f);
            metaArr[slot] = meta;
            wHarr[slot] = __float2half(w);
        }
    }
}

// ======================= P4: two-pass fine sort -> packed (w14|src18) CSR ============
__global__ __launch_bounds__(1024) void p4_buildcsr(
    const int* __restrict__ bucketStart, const int* __restrict__ bucketTotal,
    const unsigned int* __restrict__ metaArr, const __half* __restrict__ wHarr,
    unsigned int* __restrict__ packedS, int* __restrict__ rowptr) {
    __shared__ int hist[NPB];
    __shared__ int wsum[16];
    int b = blockIdx.x, tid = threadIdx.x;
    int start = bucketStart[b], count = bucketTotal[b];
    int nn = min(NPB, N_NODES - b * NPB);
    hist[tid] = 0;
    __syncthreads();
    // pass 1: histogram (coalesced global re-read)
    for (int i = tid; i < count; i += 1024)
        atomicAdd(&hist[metaArr[start + i] >> 18], 1);
    __syncthreads();
    // 1024-wide exclusive scan (each thread owns hist[tid])
    int v = hist[tid];
    int lane = tid & 63, wid = tid >> 6;
    int incl = v;
    #pragma unroll
    for (int o = 1; o < 64; o <<= 1) {
        int t = __shfl_up(incl, o, 64);
        if (lane >= o) incl += t;
    }
    if (lane == 63) wsum[wid] = incl;
    __syncthreads();
    int woff = 0;
    for (int w = 0; w < wid; ++w) woff += wsum[w];
    int excl = woff + incl - v;
    if (tid < nn) rowptr[b * NPB + tid] = start + excl;
    hist[tid] = excl;                            // becomes placement cursor
    __syncthreads();
    // pass 2: placement, pack weight as 14-bit fixed-point into high bits
    for (int i = tid; i < count; i += 1024) {
        unsigned int m = metaArr[start + i];
        float w = __half2float(wHarr[start + i]);
        unsigned int wq = (unsigned int)(w * 16383.0f + 0.5f);
        int pos = start + atomicAdd(&hist[m >> 18], 1);
        packedS[pos] = (wq << 18) | (m & 0x3FFFFu);
    }
}

// ========== agg1: wave-per-node gather-aggregate + ELU (4 edge slots x 16 ch) ========
__global__ __launch_bounds__(256) void agg1_kernel(
    const unsigned int* __restrict__ packedS, const int* __restrict__ rowptr,
    const __half2* __restrict__ hbufH, __half* __restrict__ rbufH,
    const float* __restrict__ bias1) {
    int n = blockIdx.x * 4 + (threadIdx.x >> 6);   // one wave per node
    if (n >= N_NODES) return;
    int lane = threadIdx.x & 63;
    int c = lane & 15, sub = lane >> 4;
    int beg = rowptr[n], end = rowptr[n + 1];
    float acc = 0.f;
    int p = beg + sub;
    for (; p + 4 < end; p += 8) {                  // 2x unroll: 8 lines in flight/wave
        unsigned int m0 = packedS[p];
        unsigned int m1 = packedS[p + 4];
        float w0 = (float)(m0 >> 18) * (1.0f / 16383.0f);
        float w1 = (float)(m1 >> 18) * (1.0f / 16383.0f);
        float2 h0 = __half22float2(hbufH[(size_t)(m0 & 0x3FFFFu) * HID + c]);
        float2 h1 = __half22float2(hbufH[(size_t)(m1 & 0x3FFFFu) * HID + c]);
        acc += fmaf(w0, h0.y - h0.x, h0.x);
        acc += fmaf(w1, h1.y - h1.x, h1.x);
    }
    if (p < end) {
        unsigned int m = packedS[p];
        float w = (float)(m >> 18) * (1.0f / 16383.0f);
        float2 h = __half22float2(hbufH[(size_t)(m & 0x3FFFFu) * HID + c]);
        acc += fmaf(w, h.y - h.x, h.x);
    }
    acc += __shfl_xor(acc, 16, 64);
    acc += __shfl_xor(acc, 32, 64);
    if (sub == 0) {
        float invd = 1.0f / fmaxf((float)(end - beg), 1.0f);
        float r = __half2float(rbufH[(size_t)n * HID + c]);
        float vv = fmaf(acc, invd, r) + bias1[c];
        float hv = vv > 0.f ? vv : expm1f(vv);
        rbufH[(size_t)n * HID + c] = __float2half(hv);
    }
}

// ======================= node1b: tiny layer-2 transforms =======================
__global__ __launch_bounds__(256) void node1b_kernel(
    const __half* __restrict__ rbufH, const float* __restrict__ W2,
    const float* __restrict__ root2,
    __half2* __restrict__ h2buf, float* __restrict__ r2buf) {
    int n = blockIdx.x * 256 + threadIdx.x;
    if (n >= N_NODES) return;
    float h[HID];
    #pragma unroll
    for (int k = 0; k < HID; ++k) h[k] = __half2float(rbufH[(size_t)n * HID + k]);
    float o0[NCLS], o1[NCLS], orr[NCLS];
    #pragma unroll
    for (int j = 0; j < NCLS; ++j) { o0[j] = 0.f; o1[j] = 0.f; orr[j] = 0.f; }
    const float* __restrict__ W2b = W2 + HID * NCLS;
    #pragma unroll
    for (int k = 0; k < HID; ++k) {
        #pragma unroll
        for (int j = 0; j < NCLS; ++j) {
            o0[j]  = fmaf(h[k], W2 [k * NCLS + j], o0[j]);
            o1[j]  = fmaf(h[k], W2b[k * NCLS + j], o1[j]);
            orr[j] = fmaf(h[k], root2[k * NCLS + j], orr[j]);
        }
    }
    __half2* hb = h2buf + (size_t)n * 8;
    float*   r2 = r2buf + (size_t)n * 8;
    #pragma unroll
    for (int j = 0; j < NCLS; ++j) {
        hb[j] = __floats2half2_rn(o0[j], o1[j]);
        r2[j] = orr[j];
    }
    hb[7] = __floats2half2_rn(0.f, 0.f);
    r2[7] = 0.f;
}

// ========== agg2: wave-per-node gather + log_softmax (8 edge slots x 8 ch) ===========
__global__ __launch_bounds__(256) void agg2_kernel(
    const unsigned int* __restrict__ packedS, const int* __restrict__ rowptr,
    const __half2* __restrict__ h2buf, const float* __restrict__ r2buf,
    const float* __restrict__ bias2, float* __restrict__ out) {
    int n = blockIdx.x * 4 + (threadIdx.x >> 6);   // one wave per node
    if (n >= N_NODES) return;
    int lane = threadIdx.x & 63;
    int j = lane & 7, sub = lane >> 3;
    int beg = rowptr[n], end = rowptr[n + 1];
    float acc = 0.f;
    int p = beg + sub;
    for (; p + 8 < end; p += 16) {                 // 2x unroll: 16 lines in flight/wave
        unsigned int m0 = packedS[p];
        unsigned int m1 = packedS[p + 8];
        float w0 = (float)(m0 >> 18) * (1.0f / 16383.0f);
        float w1 = (float)(m1 >> 18) * (1.0f / 16383.0f);
        float2 h0 = __half22float2(h2buf[(size_t)(m0 & 0x3FFFFu) * 8 + j]);
        float2 h1 = __half22float2(h2buf[(size_t)(m1 & 0x3FFFFu) * 8 + j]);
        acc += fmaf(w0, h0.y - h0.x, h0.x);
        acc += fmaf(w1, h1.y - h1.x, h1.x);
    }
    if (p < end) {
        unsigned int m = packedS[p];
        float w = (float)(m >> 18) * (1.0f / 16383.0f);
        float2 h = __half22float2(h2buf[(size_t)(m & 0x3FFFFu) * 8 + j]);
        acc += fmaf(w, h.y - h.x, h.x);
    }
    acc += __shfl_xor(acc, 8, 64);
    acc += __shfl_xor(acc, 16, 64);
    acc += __shfl_xor(acc, 32, 64);
    if (sub == 0) {
        float invd = 1.0f / fmaxf((float)(end - beg), 1.0f);
        float v = fmaf(acc, invd, r2buf[(size_t)n * 8 + j]) + ((j < NCLS) ? bias2[j] : 0.f);
        if (j == NCLS) v = -INFINITY;
        float mx = v;
        mx = fmaxf(mx, __shfl_xor(mx, 1, 8));
        mx = fmaxf(mx, __shfl_xor(mx, 2, 8));
        mx = fmaxf(mx, __shfl_xor(mx, 4, 8));
        float ex = expf(v - mx);
        float sm = ex;
        sm += __shfl_xor(sm, 1, 8);
        sm += __shfl_xor(sm, 2, 8);
        sm += __shfl_xor(sm, 4, 8);
        float lse = mx + logf(sm);
        if (j < NCLS) out[(size_t)n * NCLS + j] = v - lse;
    }
}

extern "C" void kernel_launch(void* const* d_in, const int* in_sizes, int n_in,
                              void* d_out, int out_size, void* d_ws, size_t ws_size,
                              hipStream_t stream) {
    const float* x     = (const float*)d_in[0];
    const float* eattr = (const float*)d_in[1];
    const int*   src   = (const int*)d_in[2];
    const int*   dst   = (const int*)d_in[3];
    const float* W1    = (const float*)d_in[4];
    const float* root1 = (const float*)d_in[5];
    const float* bias1 = (const float*)d_in[6];
    const float* W2    = (const float*)d_in[7];
    const float* root2 = (const float*)d_in[8];
    const float* bias2 = (const float*)d_in[9];
    float* out = (float*)d_out;

    // ---------- workspace layout (~85 MB) ----------
    char* wp = (char*)d_ws;
    unsigned int* metaArr = (unsigned int*)wp;  wp += (size_t)N_EDGES * 4;           // 25.6 MB
    __half*       wHarr   = (__half*)wp;        wp += (size_t)N_EDGES * 2;           // 12.8 MB
    unsigned int* packedS = (unsigned int*)wp;  wp += (size_t)N_EDGES * 4;           // 25.6 MB
    int* blockOff    = (int*)wp;                wp += (size_t)NBUCKET * NBLKE * 4;   // 306 KB
    int* bucketTotal = (int*)wp;                wp += 1024 * 4;
    int* bucketStart = (int*)wp;                wp += 1024 * 4;
    int* rowptr      = (int*)wp;                wp += (size_t)(N_NODES + 4) * 4;     // 0.8 MB
    __half* Bf       = (__half*)wp;             wp += (size_t)3 * 16 * 64 * 8 * 2;   // 48 KB
    __half2* hbufH   = (__half2*)wp;            wp += (size_t)N_NODES * HID * 4;     // 12.8 MB
    __half*  rbufH   = (__half*)wp;             wp += (size_t)N_NODES * HID * 2;     // 6.4 MB
    // aliases: hbufH region is dead after agg1
    __half2* h2buf = hbufH;                                          // N*8 half2
    float*   r2buf = (float*)(hbufH + (size_t)N_NODES * 8);          // N*8 f32

    const int node_blocks = (N_NODES + 255) / 256;  // 782
    const int wave_blocks = (N_NODES + 3) / 4;      // 50000 (4 waves/block)

    hipLaunchKernelGGL(packB_kernel, dim3((3 * 16 * 64 + 255) / 256), dim3(256), 0, stream,
                       W1, root1, Bf);
    hipLaunchKernelGGL(gemm1_kernel, dim3(N_NODES / GROWS), dim3(256), 0, stream,
                       x, Bf, hbufH, rbufH);
    hipLaunchKernelGGL(p1_bincount, dim3(NBLKE), dim3(256), 0, stream, dst, blockOff);
    hipLaunchKernelGGL(p2a_kernel, dim3(NBUCKET), dim3(256), 0, stream,
                       blockOff, bucketTotal);
    hipLaunchKernelGGL(p2b_kernel, dim3(1), dim3(256), 0, stream,
                       bucketTotal, bucketStart, rowptr);
    hipLaunchKernelGGL(p3_binscatter, dim3(NBLKE), dim3(256), 0, stream,
                       dst, src, eattr, blockOff, bucketStart, metaArr, wHarr);
    hipLaunchKernelGGL(p4_buildcsr, dim3(NBUCKET), dim3(1024), 0, stream,
                       bucketStart, bucketTotal, metaArr, wHarr, packedS, rowptr);
    hipLaunchKernelGGL(agg1_kernel, dim3(wave_blocks), dim3(256), 0, stream,
                       packedS, rowptr, hbufH, rbufH, bias1);
    hipLaunchKernelGGL(node1b_kernel, dim3(node_blocks), dim3(256), 0, stream,
                       rbufH, W2, root2, h2buf, r2buf);
    hipLaunchKernelGGL(agg2_kernel, dim3(wave_blocks), dim3(256), 0, stream,
                       packedS, rowptr, h2buf, r2buf, bias2, out);
}